// Round 1
// baseline (4237.442 us; speedup 1.0000x reference)
//
#include <hip/hip_runtime.h>
#include <hip/hip_bf16.h>
#include <math.h>

#define FEAT 1040
#define NHEAD 8
#define DHEAD 130
#define NLAYER 3
#define NGRAPH 64
#define NEG_SLOPE 0.2f
#define BN_EPS 1e-5f

// ---------------- GEMM: C[M,N] = A[M,K] * B[K,N], fp32 ----------------
#define GTM 128
#define GTN 128
#define GTK 8

__global__ __launch_bounds__(256) void gemm128(const float* __restrict__ A,
                                               const float* __restrict__ B,
                                               float* __restrict__ C,
                                               int M, int N, int K) {
    __shared__ float As[GTK][GTM + 4];
    __shared__ float Bs[GTK][GTN + 4];
    const int tid = threadIdx.x;
    const int bm = blockIdx.y * GTM;
    const int bn = blockIdx.x * GTN;
    const int tm = (tid & 15) * 8;
    const int tn = (tid >> 4) * 8;

    const int ar = tid >> 1;          // 0..127 row within A tile
    const int ak = (tid & 1) * 4;     // 0 or 4 col within A tile
    const int bk = tid >> 5;          // 0..7 row within B tile
    const int bc = (tid & 31) * 4;    // 0..124 col within B tile

    float acc[8][8];
#pragma unroll
    for (int i = 0; i < 8; i++)
#pragma unroll
        for (int j = 0; j < 8; j++) acc[i][j] = 0.f;

    for (int k0 = 0; k0 < K; k0 += GTK) {
        // A tile
        float4 av = make_float4(0.f, 0.f, 0.f, 0.f);
        int grow = bm + ar;
        if (grow < M) av = *(const float4*)(A + (size_t)grow * K + k0 + ak);
        As[ak + 0][ar] = av.x;
        As[ak + 1][ar] = av.y;
        As[ak + 2][ar] = av.z;
        As[ak + 3][ar] = av.w;
        // B tile (K is a multiple of GTK, so row always valid; guard cols)
        float4 bv = make_float4(0.f, 0.f, 0.f, 0.f);
        int gcol = bn + bc;
        if (gcol < N) bv = *(const float4*)(B + (size_t)(k0 + bk) * N + gcol);
        *(float4*)&Bs[bk][bc] = bv;
        __syncthreads();

#pragma unroll
        for (int kk = 0; kk < GTK; kk++) {
            float4 a0 = *(const float4*)&As[kk][tm];
            float4 a1 = *(const float4*)&As[kk][tm + 4];
            float4 b0 = *(const float4*)&Bs[kk][tn];
            float4 b1 = *(const float4*)&Bs[kk][tn + 4];
            float a[8] = {a0.x, a0.y, a0.z, a0.w, a1.x, a1.y, a1.z, a1.w};
            float b[8] = {b0.x, b0.y, b0.z, b0.w, b1.x, b1.y, b1.z, b1.w};
#pragma unroll
            for (int i = 0; i < 8; i++)
#pragma unroll
                for (int j = 0; j < 8; j++) acc[i][j] += a[i] * b[j];
        }
        __syncthreads();
    }

#pragma unroll
    for (int i = 0; i < 8; i++) {
        int row = bm + tm + i;
        if (row >= M) continue;
#pragma unroll
        for (int jj = 0; jj < 8; jj += 4) {
            int col = bn + tn + jj;
            if (col < N) {  // N%4==0 and col%4==0 -> full float4 in-bounds
                *(float4*)(C + (size_t)row * N + col) =
                    make_float4(acc[i][jj], acc[i][jj + 1], acc[i][jj + 2], acc[i][jj + 3]);
            }
        }
    }
}

// ---------------- graph preprocessing ----------------
__global__ void build_edges(const int* __restrict__ ei, int E, int N,
                            int* __restrict__ src2, int* __restrict__ dst2,
                            int* __restrict__ deg) {
    int e = blockIdx.x * 256 + threadIdx.x;
    int E2 = E + N;
    if (e >= E2) return;
    int s, d;
    if (e < E) { s = ei[e]; d = ei[E + e]; }
    else       { s = e - E; d = e - E; }
    src2[e] = s;
    dst2[e] = d;
    atomicAdd(&deg[d], 1);
}

__global__ void scan_kernel(const int* __restrict__ deg, int* __restrict__ off,
                            int* __restrict__ cursor, int N) {
    __shared__ int buf[1024];
    __shared__ int carry;
    if (threadIdx.x == 0) carry = 0;
    __syncthreads();
    for (int base = 0; base < N; base += 1024) {
        int i = base + threadIdx.x;
        int v = (i < N) ? deg[i] : 0;
        buf[threadIdx.x] = v;
        __syncthreads();
        for (int s = 1; s < 1024; s <<= 1) {
            int t = (threadIdx.x >= s) ? buf[threadIdx.x - s] : 0;
            __syncthreads();
            buf[threadIdx.x] += t;
            __syncthreads();
        }
        int incl = buf[threadIdx.x];
        int excl = incl - v;
        if (i < N) {
            off[i] = carry + excl;
            cursor[i] = carry + excl;
        }
        __syncthreads();
        if (threadIdx.x == 1023) carry += buf[1023];
        __syncthreads();
    }
    if (threadIdx.x == 0) off[N] = carry;
}

__global__ void scatter_k(const int* __restrict__ src2, const int* __restrict__ dst2,
                          int* __restrict__ cursor, int* __restrict__ ssrc,
                          int* __restrict__ sdst, int E2) {
    int e = blockIdx.x * 256 + threadIdx.x;
    if (e >= E2) return;
    int d = dst2[e];
    int pos = atomicAdd(&cursor[d], 1);
    ssrc[pos] = src2[e];
    sdst[pos] = d;
}

__global__ void count_k(const int* __restrict__ batch, float* __restrict__ counts, int N) {
    int n = blockIdx.x * 256 + threadIdx.x;
    if (n < N) atomicAdd(&counts[batch[n]], 1.0f);
}

// ---------------- per-layer pieces ----------------
__global__ void alpha_kernel(const float* __restrict__ xh, const float* __restrict__ a_s,
                             const float* __restrict__ a_d, float* __restrict__ asrc,
                             float* __restrict__ adst, int N) {
    int n = blockIdx.x;
    int lane = threadIdx.x;         // 64
    int h = lane >> 3, j = lane & 7;
    const float* row = xh + (size_t)n * FEAT + h * DHEAD;
    const float* as = a_s + h * DHEAD;
    const float* ad = a_d + h * DHEAD;
    float ss = 0.f, sd = 0.f;
    for (int d = j; d < DHEAD; d += 8) {
        float v = row[d];
        ss += v * as[d];
        sd += v * ad[d];
    }
#pragma unroll
    for (int o = 1; o < 8; o <<= 1) {
        ss += __shfl_xor(ss, o);
        sd += __shfl_xor(sd, o);
    }
    if (j == 0) {
        asrc[n * NHEAD + h] = ss;
        adst[n * NHEAD + h] = sd;
    }
}

__global__ void edge_logits(const int* __restrict__ ssrc, const int* __restrict__ sdst,
                            const float* __restrict__ asrc, const float* __restrict__ adst,
                            float* __restrict__ p, int E2) {
    int t = blockIdx.x * 256 + threadIdx.x;
    if (t >= E2 * NHEAD) return;
    int j = t >> 3, h = t & 7;
    float e = asrc[ssrc[j] * NHEAD + h] + adst[sdst[j] * NHEAD + h];
    p[t] = (e > 0.f) ? e : NEG_SLOPE * e;
}

__global__ void softmax_k(const int* __restrict__ off, float* __restrict__ p, int N) {
    int t = blockIdx.x * 256 + threadIdx.x;
    if (t >= N * NHEAD) return;
    int n = t >> 3, h = t & 7;
    int s = off[n], e = off[n + 1];
    float m = -INFINITY;
    for (int j = s; j < e; j++) m = fmaxf(m, p[j * NHEAD + h]);
    float sum = 0.f;
    for (int j = s; j < e; j++) {
        float v = __expf(p[j * NHEAD + h] - m);
        p[j * NHEAD + h] = v;
        sum += v;
    }
    float inv = 1.0f / sum;
    for (int j = s; j < e; j++) p[j * NHEAD + h] *= inv;
}

__global__ __launch_bounds__(256) void aggregate(
    const float* __restrict__ xh, const float* __restrict__ p,
    const int* __restrict__ off, const int* __restrict__ ssrc,
    const float* __restrict__ prev,       // may be null (layer 0)
    const float* __restrict__ b_att, const float* __restrict__ gamma,
    const float* __restrict__ beta, const float* __restrict__ mean,
    const float* __restrict__ var,
    float* __restrict__ hout,             // null on last layer
    float* __restrict__ pooled, const int* __restrict__ batch, int N) {
    int n = blockIdx.x;
    int s = off[n], e = off[n + 1];
    int fidx[5], hh[5];
    bool valid[5];
#pragma unroll
    for (int i = 0; i < 5; i++) {
        int f = threadIdx.x + i * 256;
        fidx[i] = f;
        valid[i] = (f < FEAT);
        hh[i] = valid[i] ? (f / DHEAD) : 0;
    }
    float acc[5] = {0.f, 0.f, 0.f, 0.f, 0.f};
    for (int j = s; j < e; j++) {
        int src = ssrc[j];
        const float* row = xh + (size_t)src * FEAT;
        const float* pj = p + (size_t)j * NHEAD;
#pragma unroll
        for (int i = 0; i < 5; i++) {
            if (valid[i]) acc[i] += pj[hh[i]] * row[fidx[i]];
        }
    }
#pragma unroll
    for (int i = 0; i < 5; i++) {
        if (!valid[i]) continue;
        int f = fidx[i];
        float z = acc[i] + b_att[f];
        if (prev) z += prev[(size_t)n * FEAT + f];
        z = (z - mean[f]) * rsqrtf(var[f] + BN_EPS) * gamma[f] + beta[f];
        float hn = fmaxf(z, 0.f);
        if (hout) hout[(size_t)n * FEAT + f] = hn;
        else      atomicAdd(&pooled[(size_t)batch[n] * FEAT + f], hn);
    }
}

__global__ void final_k(const float* __restrict__ pooled, const float* __restrict__ counts,
                        const float* __restrict__ W_out, const float* __restrict__ b_out,
                        float* __restrict__ out) {
    int g = blockIdx.x >> 1, c = blockIdx.x & 1;
    int lane = threadIdx.x;  // 64
    float ssum = 0.f;
    for (int f = lane; f < FEAT; f += 64) ssum += pooled[(size_t)g * FEAT + f] * W_out[f * 2 + c];
#pragma unroll
    for (int o = 1; o < 64; o <<= 1) ssum += __shfl_xor(ssum, o);
    if (lane == 0) {
        float inv = 1.0f / fmaxf(counts[g], 1.0f);
        out[g * 2 + c] = ssum * inv + b_out[c];
    }
}

// ---------------- launch ----------------
extern "C" void kernel_launch(void* const* d_in, const int* in_sizes, int n_in,
                              void* d_out, int out_size, void* d_ws, size_t ws_size,
                              hipStream_t stream) {
    const float* x       = (const float*)d_in[0];
    const int*   ei      = (const int*)d_in[1];
    const int*   batch   = (const int*)d_in[2];
    const float* W       = (const float*)d_in[3];
    const float* a_src   = (const float*)d_in[4];
    const float* a_dst   = (const float*)d_in[5];
    const float* b_att   = (const float*)d_in[6];
    const float* gamma   = (const float*)d_in[7];
    const float* beta    = (const float*)d_in[8];
    const float* r_mean  = (const float*)d_in[9];
    const float* r_var   = (const float*)d_in[10];
    const float* W_out   = (const float*)d_in[11];
    const float* b_out   = (const float*)d_in[12];
    float* out = (float*)d_out;

    const int N = in_sizes[0] / FEAT;
    const int E = in_sizes[1] / 2;
    const int E2 = E + N;

    // workspace carve-up
    char* w = (char*)d_ws;
    auto alloc = [&](size_t bytes) {
        void* pp = (void*)w;
        w += (bytes + 255) & ~(size_t)255;
        return pp;
    };
    float* xh     = (float*)alloc((size_t)N * FEAT * 4);
    float* hA     = (float*)alloc((size_t)N * FEAT * 4);
    float* hB     = (float*)alloc((size_t)N * FEAT * 4);
    float* p      = (float*)alloc((size_t)E2 * NHEAD * 4);
    float* asrc   = (float*)alloc((size_t)N * NHEAD * 4);
    float* adst   = (float*)alloc((size_t)N * NHEAD * 4);
    int*   src2   = (int*)alloc((size_t)E2 * 4);
    int*   dst2   = (int*)alloc((size_t)E2 * 4);
    int*   ssrc   = (int*)alloc((size_t)E2 * 4);
    int*   sdst   = (int*)alloc((size_t)E2 * 4);
    int*   deg    = (int*)alloc((size_t)N * 4);
    int*   off    = (int*)alloc((size_t)(N + 1) * 4);
    int*   cursor = (int*)alloc((size_t)N * 4);
    float* pooled = (float*)alloc((size_t)NGRAPH * FEAT * 4);
    float* counts = (float*)alloc((size_t)NGRAPH * 4);

    // zero-init what needs it (ws is poisoned 0xAA before every launch)
    hipMemsetAsync(deg, 0, (size_t)N * 4, stream);
    hipMemsetAsync(pooled, 0, (size_t)NGRAPH * FEAT * 4, stream);
    hipMemsetAsync(counts, 0, (size_t)NGRAPH * 4, stream);

    // graph preprocessing (shared across layers)
    build_edges<<<(E2 + 255) / 256, 256, 0, stream>>>(ei, E, N, src2, dst2, deg);
    scan_kernel<<<1, 1024, 0, stream>>>(deg, off, cursor, N);
    scatter_k<<<(E2 + 255) / 256, 256, 0, stream>>>(src2, dst2, cursor, ssrc, sdst, E2);
    count_k<<<(N + 255) / 256, 256, 0, stream>>>(batch, counts, N);

    const float* hin[NLAYER]   = {x, hA, hB};
    const float* hprev[NLAYER] = {nullptr, x, hA};
    float* houtl[NLAYER]       = {hA, hB, nullptr};

    dim3 ggrid((FEAT + GTN - 1) / GTN, (N + GTM - 1) / GTM);
    for (int l = 0; l < NLAYER; l++) {
        gemm128<<<ggrid, 256, 0, stream>>>(hin[l], W + (size_t)l * FEAT * FEAT, xh, N, FEAT, FEAT);
        alpha_kernel<<<N, 64, 0, stream>>>(xh, a_src + l * FEAT, a_dst + l * FEAT, asrc, adst, N);
        edge_logits<<<(E2 * NHEAD + 255) / 256, 256, 0, stream>>>(ssrc, sdst, asrc, adst, p, E2);
        softmax_k<<<(N * NHEAD + 255) / 256, 256, 0, stream>>>(off, p, N);
        aggregate<<<N, 256, 0, stream>>>(xh, p, off, ssrc, hprev[l],
                                         b_att + l * FEAT, gamma + l * FEAT, beta + l * FEAT,
                                         r_mean + l * FEAT, r_var + l * FEAT,
                                         houtl[l], pooled, batch, N);
    }

    final_k<<<NGRAPH * 2, 64, 0, stream>>>(pooled, counts, W_out, b_out, out);
}

// Round 2
// 2100.428 us; speedup vs baseline: 2.0174x; 2.0174x over previous
//
#include <hip/hip_runtime.h>
#include <hip/hip_bf16.h>
#include <math.h>

#define FEAT 1040
#define NHEAD 8
#define DHEAD 130
#define NLAYER 3
#define NGRAPH 64
#define NEG_SLOPE 0.2f
#define BN_EPS 1e-5f
#define KP 1056   // FEAT padded to multiple of 32 (K of GEMM)
#define NP 1152   // FEAT padded to multiple of 128 (N of GEMM)

typedef float floatx4 __attribute__((ext_vector_type(4)));
typedef short shortx8 __attribute__((ext_vector_type(8)));

__device__ __forceinline__ short f2bf(float f) {
    unsigned u = __float_as_uint(f);
    u += 0x7fff + ((u >> 16) & 1);   // round-to-nearest-even
    return (short)(u >> 16);
}
__device__ __forceinline__ float bf2f(short b) {
    return __uint_as_float(((unsigned)(unsigned short)b) << 16);
}

__device__ __forceinline__ void async16(const void* g, void* l) {
    __builtin_amdgcn_global_load_lds(
        (const __attribute__((address_space(1))) unsigned int*)g,
        (__attribute__((address_space(3))) unsigned int*)l, 16, 0, 0);
}

// ---------------- bf16 MFMA GEMM: C[M,1040] = A[Mp,KP] * Bt[NP,KP]^T ----------
// A row-major [Mp][KP] bf16 (zero-padded); Bt row-major [NP][KP] bf16 = B^T.
// LDS layout (per 128x32 tile): [block16][kgroup(4)][row16][8] -- linear order
// equals thread*8 during staging, and ds_read_b128 reads 1024 contiguous
// bytes per wave (free 2-way bank aliasing only).
__global__ __launch_bounds__(256) void gemm_mfma(const short* __restrict__ A,
                                                 const short* __restrict__ Bt,
                                                 float* __restrict__ C,
                                                 int M) {
    __shared__ short As[128 * 32];
    __shared__ short Bs[128 * 32];
    const int tid = threadIdx.x;
    const int lane = tid & 63;
    const int w = tid >> 6;
    const int wm = (w & 1) * 64;   // wave row offset in tile
    const int wn = (w >> 1) * 64;  // wave col offset in tile
    const int bm = blockIdx.y * 128;
    const int bn = blockIdx.x * 128;

    // staging decode for rounds r=0,1: tt = r*256 + tid
    const int tt0 = tid, tt1 = 256 + tid;
    const int row0 = ((tt0 >> 6) << 4) | (tt0 & 15);
    const int col0 = ((tt0 >> 4) & 3) * 8;
    const int row1 = ((tt1 >> 6) << 4) | (tt1 & 15);
    const int col1 = ((tt1 >> 4) & 3) * 8;

    const short* gA0 = A + (size_t)(bm + row0) * KP + col0;
    const short* gA1 = A + (size_t)(bm + row1) * KP + col1;
    const short* gB0 = Bt + (size_t)(bn + row0) * KP + col0;
    const short* gB1 = Bt + (size_t)(bn + row1) * KP + col1;
    short* lA0 = &As[tt0 * 8];
    short* lA1 = &As[tt1 * 8];
    short* lB0 = &Bs[tt0 * 8];
    short* lB1 = &Bs[tt1 * 8];

    const int fr = lane & 15;         // fragment row (m or n within 16-tile)
    const int kq = lane >> 4;         // k-group 0..3

    floatx4 acc[4][4];
#pragma unroll
    for (int i = 0; i < 4; i++)
#pragma unroll
        for (int j = 0; j < 4; j++) acc[i][j] = (floatx4){0.f, 0.f, 0.f, 0.f};

    for (int k0 = 0; k0 < KP; k0 += 32) {
        async16(gA0 + k0, lA0);
        async16(gA1 + k0, lA1);
        async16(gB0 + k0, lB0);
        async16(gB1 + k0, lB1);
        __syncthreads();   // drains vmcnt then barrier

        shortx8 af[4], bfr[4];
#pragma unroll
        for (int i = 0; i < 4; i++) {
            af[i]  = *(const shortx8*)&As[((wm >> 4) + i) * 512 + kq * 128 + fr * 8];
            bfr[i] = *(const shortx8*)&Bs[((wn >> 4) + i) * 512 + kq * 128 + fr * 8];
        }
#pragma unroll
        for (int i = 0; i < 4; i++)
#pragma unroll
            for (int j = 0; j < 4; j++)
                acc[i][j] = __builtin_amdgcn_mfma_f32_16x16x32_bf16(af[i], bfr[j], acc[i][j], 0, 0, 0);
        __syncthreads();
    }

    // C/D layout: col = lane&15, row = (lane>>4)*4 + reg
    const int rbase = (lane >> 4) * 4;
    const int ccol = lane & 15;
#pragma unroll
    for (int j = 0; j < 4; j++) {
        int col = bn + wn + j * 16 + ccol;
        if (bn + wn + j * 16 >= FEAT) continue;   // 1040 % 16 == 0: tile-uniform
#pragma unroll
        for (int i = 0; i < 4; i++) {
#pragma unroll
            for (int r = 0; r < 4; r++) {
                int row = bm + wm + i * 16 + rbase + r;
                if (row < M) C[(size_t)row * FEAT + col] = acc[i][j][r];
            }
        }
    }
}

// ---------------- conversions / padding ----------------
__global__ void conv_x_bf(const float* __restrict__ x, short* __restrict__ out, int N) {
    int idx = blockIdx.x * 256 + threadIdx.x;
    if (idx >= N * FEAT) return;
    int r = idx / FEAT, c = idx - r * FEAT;
    out[(size_t)r * KP + c] = f2bf(x[idx]);
}

// zero pad cols [1040,KP) for every row; zero whole rows >= Mvalid
__global__ void pad_bf(short* __restrict__ buf, int Mvalid) {
    int r = blockIdx.x;
    short* row = buf + (size_t)r * KP;
    if (r < Mvalid) {
        if (threadIdx.x < KP - FEAT) row[FEAT + threadIdx.x] = 0;
    } else {
        for (int c = threadIdx.x; c < KP; c += 64) row[c] = 0;
    }
}

// Bt[n][k] = bf16(W[k*1040 + n]) via LDS tile transpose
__global__ void transpose_w(const float* __restrict__ Wl, short* __restrict__ Bt) {
    __shared__ float t[32][33];
    int kb = blockIdx.x * 32, nb = blockIdx.y * 32;
    int tx = threadIdx.x & 31, ty = threadIdx.x >> 5;  // 32 x 8
#pragma unroll
    for (int i = 0; i < 4; i++) {
        int k = kb + ty + i * 8, n = nb + tx;
        t[ty + i * 8][tx] = (k < FEAT && n < FEAT) ? Wl[(size_t)k * FEAT + n] : 0.f;
    }
    __syncthreads();
#pragma unroll
    for (int i = 0; i < 4; i++) {
        int n = nb + ty + i * 8, k = kb + tx;
        if (n < FEAT && k < FEAT) Bt[(size_t)n * KP + k] = f2bf(t[tx][ty + i * 8]);
    }
}

// ---------------- graph preprocessing ----------------
__global__ void build_edges(const int* __restrict__ ei, int E, int N,
                            int* __restrict__ src2, int* __restrict__ dst2,
                            int* __restrict__ deg) {
    int e = blockIdx.x * 256 + threadIdx.x;
    int E2 = E + N;
    if (e >= E2) return;
    int s, d;
    if (e < E) { s = ei[e]; d = ei[E + e]; }
    else       { s = e - E; d = e - E; }
    src2[e] = s;
    dst2[e] = d;
    atomicAdd(&deg[d], 1);
}

__global__ void scan_kernel(const int* __restrict__ deg, int* __restrict__ off,
                            int* __restrict__ cursor, int N) {
    __shared__ int buf[1024];
    __shared__ int carry;
    if (threadIdx.x == 0) carry = 0;
    __syncthreads();
    for (int base = 0; base < N; base += 1024) {
        int i = base + threadIdx.x;
        int v = (i < N) ? deg[i] : 0;
        buf[threadIdx.x] = v;
        __syncthreads();
        for (int s = 1; s < 1024; s <<= 1) {
            int t = (threadIdx.x >= s) ? buf[threadIdx.x - s] : 0;
            __syncthreads();
            buf[threadIdx.x] += t;
            __syncthreads();
        }
        int incl = buf[threadIdx.x];
        int excl = incl - v;
        if (i < N) {
            off[i] = carry + excl;
            cursor[i] = carry + excl;
        }
        __syncthreads();
        if (threadIdx.x == 1023) carry += buf[1023];
        __syncthreads();
    }
    if (threadIdx.x == 0) off[N] = carry;
}

__global__ void scatter_k(const int* __restrict__ src2, const int* __restrict__ dst2,
                          int* __restrict__ cursor, int* __restrict__ ssrc,
                          int* __restrict__ sdst, int E2) {
    int e = blockIdx.x * 256 + threadIdx.x;
    if (e >= E2) return;
    int d = dst2[e];
    int pos = atomicAdd(&cursor[d], 1);
    ssrc[pos] = src2[e];
    sdst[pos] = d;
}

__global__ void count_k(const int* __restrict__ batch, float* __restrict__ counts, int N) {
    int n = blockIdx.x * 256 + threadIdx.x;
    if (n < N) atomicAdd(&counts[batch[n]], 1.0f);
}

// ---------------- per-layer pieces ----------------
__global__ void alpha_kernel(const float* __restrict__ xh, const float* __restrict__ a_s,
                             const float* __restrict__ a_d, float* __restrict__ asrc,
                             float* __restrict__ adst, int N) {
    int n = blockIdx.x;
    int lane = threadIdx.x;         // 64
    int h = lane >> 3, j = lane & 7;
    const float* row = xh + (size_t)n * FEAT + h * DHEAD;
    const float* as = a_s + h * DHEAD;
    const float* ad = a_d + h * DHEAD;
    float ss = 0.f, sd = 0.f;
    for (int d = j; d < DHEAD; d += 8) {
        float v = row[d];
        ss += v * as[d];
        sd += v * ad[d];
    }
#pragma unroll
    for (int o = 1; o < 8; o <<= 1) {
        ss += __shfl_xor(ss, o);
        sd += __shfl_xor(sd, o);
    }
    if (j == 0) {
        asrc[n * NHEAD + h] = ss;
        adst[n * NHEAD + h] = sd;
    }
}

__global__ void edge_logits(const int* __restrict__ ssrc, const int* __restrict__ sdst,
                            const float* __restrict__ asrc, const float* __restrict__ adst,
                            float* __restrict__ p, int E2) {
    int t = blockIdx.x * 256 + threadIdx.x;
    if (t >= E2 * NHEAD) return;
    int j = t >> 3, h = t & 7;
    float e = asrc[ssrc[j] * NHEAD + h] + adst[sdst[j] * NHEAD + h];
    p[t] = (e > 0.f) ? e : NEG_SLOPE * e;
}

__global__ void softmax_k(const int* __restrict__ off, float* __restrict__ p, int N) {
    int t = blockIdx.x * 256 + threadIdx.x;
    if (t >= N * NHEAD) return;
    int n = t >> 3, h = t & 7;
    int s = off[n], e = off[n + 1];
    float m = -INFINITY;
    for (int j = s; j < e; j++) m = fmaxf(m, p[j * NHEAD + h]);
    float sum = 0.f;
    for (int j = s; j < e; j++) {
        float v = __expf(p[j * NHEAD + h] - m);
        p[j * NHEAD + h] = v;
        sum += v;
    }
    float inv = 1.0f / sum;
    for (int j = s; j < e; j++) p[j * NHEAD + h] *= inv;
}

__global__ __launch_bounds__(256) void aggregate(
    const float* __restrict__ xh, const float* __restrict__ p,
    const int* __restrict__ off, const int* __restrict__ ssrc,
    const float* __restrict__ prev_f,     // fp32 residual (layer 1: x) or null
    const short* __restrict__ prev_bf,    // bf16 residual (layer 2: hA_bf) or null
    const float* __restrict__ b_att, const float* __restrict__ gamma,
    const float* __restrict__ beta, const float* __restrict__ mean,
    const float* __restrict__ var,
    short* __restrict__ hout_bf,          // bf16 h for next layer (null on last)
    float* __restrict__ pooled, const int* __restrict__ batch, int N) {
    int n = blockIdx.x;
    int s = off[n], e = off[n + 1];
    int fidx[5], hh[5];
    bool valid[5];
#pragma unroll
    for (int i = 0; i < 5; i++) {
        int f = threadIdx.x + i * 256;
        fidx[i] = f;
        valid[i] = (f < FEAT);
        hh[i] = valid[i] ? (f / DHEAD) : 0;
    }
    float acc[5] = {0.f, 0.f, 0.f, 0.f, 0.f};
    for (int j = s; j < e; j++) {
        int src = ssrc[j];
        const float* row = xh + (size_t)src * FEAT;
        const float* pj = p + (size_t)j * NHEAD;
#pragma unroll
        for (int i = 0; i < 5; i++) {
            if (valid[i]) acc[i] += pj[hh[i]] * row[fidx[i]];
        }
    }
#pragma unroll
    for (int i = 0; i < 5; i++) {
        if (!valid[i]) continue;
        int f = fidx[i];
        float z = acc[i] + b_att[f];
        if (prev_f)  z += prev_f[(size_t)n * FEAT + f];
        if (prev_bf) z += bf2f(prev_bf[(size_t)n * KP + f]);
        z = (z - mean[f]) * rsqrtf(var[f] + BN_EPS) * gamma[f] + beta[f];
        float hn = fmaxf(z, 0.f);
        if (hout_bf) hout_bf[(size_t)n * KP + f] = f2bf(hn);
        else         atomicAdd(&pooled[(size_t)batch[n] * FEAT + f], hn);
    }
}

__global__ void final_k(const float* __restrict__ pooled, const float* __restrict__ counts,
                        const float* __restrict__ W_out, const float* __restrict__ b_out,
                        float* __restrict__ out) {
    int g = blockIdx.x >> 1, c = blockIdx.x & 1;
    int lane = threadIdx.x;  // 64
    float ssum = 0.f;
    for (int f = lane; f < FEAT; f += 64) ssum += pooled[(size_t)g * FEAT + f] * W_out[f * 2 + c];
#pragma unroll
    for (int o = 1; o < 64; o <<= 1) ssum += __shfl_xor(ssum, o);
    if (lane == 0) {
        float inv = 1.0f / fmaxf(counts[g], 1.0f);
        out[g * 2 + c] = ssum * inv + b_out[c];
    }
}

// ---------------- launch ----------------
extern "C" void kernel_launch(void* const* d_in, const int* in_sizes, int n_in,
                              void* d_out, int out_size, void* d_ws, size_t ws_size,
                              hipStream_t stream) {
    const float* x       = (const float*)d_in[0];
    const int*   ei      = (const int*)d_in[1];
    const int*   batch   = (const int*)d_in[2];
    const float* W       = (const float*)d_in[3];
    const float* a_src   = (const float*)d_in[4];
    const float* a_dst   = (const float*)d_in[5];
    const float* b_att   = (const float*)d_in[6];
    const float* gamma   = (const float*)d_in[7];
    const float* beta    = (const float*)d_in[8];
    const float* r_mean  = (const float*)d_in[9];
    const float* r_var   = (const float*)d_in[10];
    const float* W_out   = (const float*)d_in[11];
    const float* b_out   = (const float*)d_in[12];
    float* out = (float*)d_out;

    const int N = in_sizes[0] / FEAT;
    const int E = in_sizes[1] / 2;
    const int E2 = E + N;
    const int MT = (N + 127) / 128;   // M tiles
    const int Mp = MT * 128;          // padded rows

    // workspace carve-up
    char* w = (char*)d_ws;
    auto alloc = [&](size_t bytes) {
        void* pp = (void*)w;
        w += (bytes + 255) & ~(size_t)255;
        return pp;
    };
    float* xh     = (float*)alloc((size_t)N * FEAT * 4);        // GEMM out (fp32)
    short* x_bf   = (short*)alloc((size_t)Mp * KP * 2);         // bf16 A buffers
    short* hA_bf  = (short*)alloc((size_t)Mp * KP * 2);
    short* hB_bf  = (short*)alloc((size_t)Mp * KP * 2);
    short* Bt3    = (short*)alloc((size_t)NLAYER * NP * KP * 2);// bf16 W^T
    float* p      = (float*)alloc((size_t)E2 * NHEAD * 4);
    float* asrc   = (float*)alloc((size_t)N * NHEAD * 4);
    float* adst   = (float*)alloc((size_t)N * NHEAD * 4);
    int*   src2   = (int*)alloc((size_t)E2 * 4);
    int*   dst2   = (int*)alloc((size_t)E2 * 4);
    int*   ssrc   = (int*)alloc((size_t)E2 * 4);
    int*   sdst   = (int*)alloc((size_t)E2 * 4);
    int*   deg    = (int*)alloc((size_t)N * 4);
    int*   off    = (int*)alloc((size_t)(N + 1) * 4);
    int*   cursor = (int*)alloc((size_t)N * 4);
    float* pooled = (float*)alloc((size_t)NGRAPH * FEAT * 4);
    float* counts = (float*)alloc((size_t)NGRAPH * 4);

    hipMemsetAsync(deg, 0, (size_t)N * 4, stream);
    hipMemsetAsync(pooled, 0, (size_t)NGRAPH * FEAT * 4, stream);
    hipMemsetAsync(counts, 0, (size_t)NGRAPH * 4, stream);
    hipMemsetAsync(Bt3, 0, (size_t)NLAYER * NP * KP * 2, stream);

    // bf16 conversions + padding
    conv_x_bf<<<(N * FEAT + 255) / 256, 256, 0, stream>>>(x, x_bf, N);
    pad_bf<<<Mp, 64, 0, stream>>>(x_bf, N);
    pad_bf<<<Mp, 64, 0, stream>>>(hA_bf, N);   // pads only; valid rows written later
    pad_bf<<<Mp, 64, 0, stream>>>(hB_bf, N);
    dim3 tgrid((FEAT + 31) / 32, (FEAT + 31) / 32);
    for (int l = 0; l < NLAYER; l++)
        transpose_w<<<tgrid, 256, 0, stream>>>(W + (size_t)l * FEAT * FEAT,
                                               Bt3 + (size_t)l * NP * KP);

    // graph preprocessing (shared across layers)
    build_edges<<<(E2 + 255) / 256, 256, 0, stream>>>(ei, E, N, src2, dst2, deg);
    scan_kernel<<<1, 1024, 0, stream>>>(deg, off, cursor, N);
    scatter_k<<<(E2 + 255) / 256, 256, 0, stream>>>(src2, dst2, cursor, ssrc, sdst, E2);
    count_k<<<(N + 255) / 256, 256, 0, stream>>>(batch, counts, N);

    const short* hin[NLAYER]     = {x_bf, hA_bf, hB_bf};
    const float* prevf[NLAYER]   = {nullptr, x, nullptr};
    const short* prevbf[NLAYER]  = {nullptr, nullptr, hA_bf};
    short* houtl[NLAYER]         = {hA_bf, hB_bf, nullptr};

    dim3 ggrid(NP / 128, MT);
    for (int l = 0; l < NLAYER; l++) {
        gemm_mfma<<<ggrid, 256, 0, stream>>>(hin[l], Bt3 + (size_t)l * NP * KP, xh, N);
        alpha_kernel<<<N, 64, 0, stream>>>(xh, a_src + l * FEAT, a_dst + l * FEAT, asrc, adst, N);
        edge_logits<<<(E2 * NHEAD + 255) / 256, 256, 0, stream>>>(ssrc, sdst, asrc, adst, p, E2);
        softmax_k<<<(N * NHEAD + 255) / 256, 256, 0, stream>>>(off, p, N);
        aggregate<<<N, 256, 0, stream>>>(xh, p, off, ssrc, prevf[l], prevbf[l],
                                         b_att + l * FEAT, gamma + l * FEAT, beta + l * FEAT,
                                         r_mean + l * FEAT, r_var + l * FEAT,
                                         houtl[l], pooled, batch, N);
    }

    final_k<<<NGRAPH * 2, 64, 0, stream>>>(pooled, counts, W_out, b_out, out);
}

// Round 3
// 2039.963 us; speedup vs baseline: 2.0772x; 1.0296x over previous
//
#include <hip/hip_runtime.h>
#include <hip/hip_bf16.h>
#include <math.h>

#define FEAT 1040
#define NHEAD 8
#define DHEAD 130
#define NLAYER 3
#define NGRAPH 64
#define NEG_SLOPE 0.2f
#define BN_EPS 1e-5f
#define KP 1056   // FEAT padded to multiple of 32 (K of GEMM)
#define NP 1152   // FEAT padded to multiple of 128 (N of GEMM); cols 1040..1055 = wa_src/wa_dst

typedef float floatx4 __attribute__((ext_vector_type(4)));
typedef short shortx8 __attribute__((ext_vector_type(8)));

__device__ __forceinline__ short f2bf(float f) {
    unsigned u = __float_as_uint(f);
    u += 0x7fff + ((u >> 16) & 1);   // round-to-nearest-even
    return (short)(u >> 16);
}
__device__ __forceinline__ float bf2f(short b) {
    return __uint_as_float(((unsigned)(unsigned short)b) << 16);
}

__device__ __forceinline__ void async16(const void* g, void* l) {
    __builtin_amdgcn_global_load_lds(
        (const __attribute__((address_space(1))) unsigned int*)g,
        (__attribute__((address_space(3))) unsigned int*)l, 16, 0, 0);
}

// ---------------- bf16 MFMA GEMM ----------------
// A row-major [Mp][KP] bf16 (zero-padded); Bt row-major [NP][KP] bf16.
// Bt rows 0..1039 = W^T; rows 1040..1047 = (W·a_src)^T; 1048..1055 = (W·a_dst)^T.
// Epilogue: cols <1040 -> xh_bf (bf16); cols 1040..1055 -> asrc/adst fp32.
__global__ __launch_bounds__(256) void gemm_mfma(const short* __restrict__ A,
                                                 const short* __restrict__ Bt,
                                                 short* __restrict__ xh_bf,
                                                 float* __restrict__ asrc,
                                                 float* __restrict__ adst,
                                                 int M) {
    __shared__ short As[128 * 32];
    __shared__ short Bs[128 * 32];
    const int tid = threadIdx.x;
    const int lane = tid & 63;
    const int w = tid >> 6;
    const int wm = (w & 1) * 64;
    const int wn = (w >> 1) * 64;
    const int bm = blockIdx.y * 128;
    const int bn = blockIdx.x * 128;

    const int tt0 = tid, tt1 = 256 + tid;
    const int row0 = ((tt0 >> 6) << 4) | (tt0 & 15);
    const int col0 = ((tt0 >> 4) & 3) * 8;
    const int row1 = ((tt1 >> 6) << 4) | (tt1 & 15);
    const int col1 = ((tt1 >> 4) & 3) * 8;

    const short* gA0 = A + (size_t)(bm + row0) * KP + col0;
    const short* gA1 = A + (size_t)(bm + row1) * KP + col1;
    const short* gB0 = Bt + (size_t)(bn + row0) * KP + col0;
    const short* gB1 = Bt + (size_t)(bn + row1) * KP + col1;
    short* lA0 = &As[tt0 * 8];
    short* lA1 = &As[tt1 * 8];
    short* lB0 = &Bs[tt0 * 8];
    short* lB1 = &Bs[tt1 * 8];

    const int fr = lane & 15;
    const int kq = lane >> 4;

    floatx4 acc[4][4];
#pragma unroll
    for (int i = 0; i < 4; i++)
#pragma unroll
        for (int j = 0; j < 4; j++) acc[i][j] = (floatx4){0.f, 0.f, 0.f, 0.f};

    for (int k0 = 0; k0 < KP; k0 += 32) {
        async16(gA0 + k0, lA0);
        async16(gA1 + k0, lA1);
        async16(gB0 + k0, lB0);
        async16(gB1 + k0, lB1);
        __syncthreads();

        shortx8 af[4], bfr[4];
#pragma unroll
        for (int i = 0; i < 4; i++) {
            af[i]  = *(const shortx8*)&As[((wm >> 4) + i) * 512 + kq * 128 + fr * 8];
            bfr[i] = *(const shortx8*)&Bs[((wn >> 4) + i) * 512 + kq * 128 + fr * 8];
        }
#pragma unroll
        for (int i = 0; i < 4; i++)
#pragma unroll
            for (int j = 0; j < 4; j++)
                acc[i][j] = __builtin_amdgcn_mfma_f32_16x16x32_bf16(af[i], bfr[j], acc[i][j], 0, 0, 0);
        __syncthreads();
    }

    // C/D layout: col = lane&15, row = (lane>>4)*4 + reg
    const int rbase = (lane >> 4) * 4;
    const int ccol = lane & 15;
#pragma unroll
    for (int j = 0; j < 4; j++) {
        int colbase = bn + wn + j * 16;
        if (colbase < FEAT) {
            int col = colbase + ccol;
#pragma unroll
            for (int i = 0; i < 4; i++)
#pragma unroll
                for (int r = 0; r < 4; r++) {
                    int row = bm + wm + i * 16 + rbase + r;
                    if (row < M) xh_bf[(size_t)row * FEAT + col] = f2bf(acc[i][j][r]);
                }
        } else if (colbase == FEAT) {  // alpha tile: cols 1040..1055
            int c = ccol;              // 0..15
            float* tgt = (c < 8) ? asrc : adst;
            int h = c & 7;
#pragma unroll
            for (int i = 0; i < 4; i++)
#pragma unroll
                for (int r = 0; r < 4; r++) {
                    int row = bm + wm + i * 16 + rbase + r;
                    if (row < M) tgt[(size_t)row * NHEAD + h] = acc[i][j][r];
                }
        }
    }
}

// ---------------- conversions / padding ----------------
__global__ void conv_x_bf(const float* __restrict__ x, short* __restrict__ out, int N) {
    int idx = blockIdx.x * 256 + threadIdx.x;
    if (idx >= N * FEAT) return;
    int r = idx / FEAT, c = idx - r * FEAT;
    out[(size_t)r * KP + c] = f2bf(x[idx]);
}

__global__ void pad_bf(short* __restrict__ buf, int Mvalid) {
    int r = blockIdx.x;
    short* row = buf + (size_t)r * KP;
    if (r < Mvalid) {
        if (threadIdx.x < KP - FEAT) row[FEAT + threadIdx.x] = 0;
    } else {
        for (int c = threadIdx.x; c < KP; c += 64) row[c] = 0;
    }
}

// Bt[n][k] = bf16(W[k*1040 + n])
__global__ void transpose_w(const float* __restrict__ Wl, short* __restrict__ Bt) {
    __shared__ float t[32][33];
    int kb = blockIdx.x * 32, nb = blockIdx.y * 32;
    int tx = threadIdx.x & 31, ty = threadIdx.x >> 5;
#pragma unroll
    for (int i = 0; i < 4; i++) {
        int k = kb + ty + i * 8, n = nb + tx;
        t[ty + i * 8][tx] = (k < FEAT && n < FEAT) ? Wl[(size_t)k * FEAT + n] : 0.f;
    }
    __syncthreads();
#pragma unroll
    for (int i = 0; i < 4; i++) {
        int n = nb + ty + i * 8, k = kb + tx;
        if (n < FEAT && k < FEAT) Bt[(size_t)n * KP + k] = f2bf(t[tx][ty + i * 8]);
    }
}

// wa rows of Bt: row (1040+h) = sum_d W[.,h,d]*a_src[h,d]; row (1048+h) same with a_dst
__global__ void wa_kernel(const float* __restrict__ W, const float* __restrict__ a_s,
                          const float* __restrict__ a_d, short* __restrict__ Bt3) {
    int t = blockIdx.x * 256 + threadIdx.x;
    if (t >= NLAYER * FEAT * NHEAD) return;
    int h = t & 7;
    int f = (t >> 3) % FEAT;
    int l = t / (FEAT * NHEAD);
    const float* wrow = W + (((size_t)l * FEAT + f) * NHEAD + h) * DHEAD;
    const float* as = a_s + ((size_t)l * NHEAD + h) * DHEAD;
    const float* ad = a_d + ((size_t)l * NHEAD + h) * DHEAD;
    float ws = 0.f, wd = 0.f;
    for (int d = 0; d < DHEAD; d++) {
        float wv = wrow[d];
        ws += wv * as[d];
        wd += wv * ad[d];
    }
    short* base = Bt3 + (size_t)l * NP * KP;
    base[(size_t)(FEAT + h) * KP + f] = f2bf(ws);
    base[(size_t)(FEAT + 8 + h) * KP + f] = f2bf(wd);
}

// ---------------- graph preprocessing ----------------
__global__ void build_edges(const int* __restrict__ ei, int E, int N,
                            int* __restrict__ src2, int* __restrict__ dst2,
                            int* __restrict__ deg) {
    int e = blockIdx.x * 256 + threadIdx.x;
    int E2 = E + N;
    if (e >= E2) return;
    int s, d;
    if (e < E) { s = ei[e]; d = ei[E + e]; }
    else       { s = e - E; d = e - E; }
    src2[e] = s;
    dst2[e] = d;
    atomicAdd(&deg[d], 1);
}

__global__ void scan_kernel(const int* __restrict__ deg, int* __restrict__ off,
                            int* __restrict__ cursor, int N) {
    __shared__ int wsum[16];
    __shared__ int carry_s;
    int tid = threadIdx.x;           // 1024
    int lane = tid & 63, wid = tid >> 6;
    if (tid == 0) carry_s = 0;
    __syncthreads();
    for (int base = 0; base < N; base += 1024) {
        int i = base + tid;
        int v = (i < N) ? deg[i] : 0;
        int incl = v;
#pragma unroll
        for (int o = 1; o < 64; o <<= 1) {
            int u = __shfl_up(incl, o);
            if (lane >= o) incl += u;
        }
        if (lane == 63) wsum[wid] = incl;
        __syncthreads();
        if (wid == 0) {
            int wv = (lane < 16) ? wsum[lane] : 0;
            int wincl = wv;
#pragma unroll
            for (int o = 1; o < 16; o <<= 1) {
                int u = __shfl_up(wincl, o);
                if (lane >= o) wincl += u;
            }
            if (lane < 16) wsum[lane] = wincl - wv;   // exclusive wave offsets
        }
        __syncthreads();
        int excl = carry_s + wsum[wid] + incl - v;
        if (i < N) { off[i] = excl; cursor[i] = excl; }
        int tot = 0;
        if (tid == 1023) tot = wsum[15] + incl;
        __syncthreads();
        if (tid == 1023) carry_s += tot;
        __syncthreads();
    }
    if (threadIdx.x == 0) off[N] = carry_s;
}

__global__ void scatter_k(const int* __restrict__ src2, const int* __restrict__ dst2,
                          int* __restrict__ cursor, int* __restrict__ ssrc,
                          int* __restrict__ sdst, int E2) {
    int e = blockIdx.x * 256 + threadIdx.x;
    if (e >= E2) return;
    int d = dst2[e];
    int pos = atomicAdd(&cursor[d], 1);
    ssrc[pos] = src2[e];
    sdst[pos] = d;
}

__global__ void count_k(const int* __restrict__ batch, float* __restrict__ counts, int N) {
    int n = blockIdx.x * 256 + threadIdx.x;
    if (n < N) atomicAdd(&counts[batch[n]], 1.0f);
}

// ---------------- fused leaky-relu + segment softmax ----------------
__global__ void att_softmax(const int* __restrict__ off, const int* __restrict__ ssrc,
                            const float* __restrict__ asrc, const float* __restrict__ adst,
                            float* __restrict__ p, int N) {
    int t = blockIdx.x * 256 + threadIdx.x;
    if (t >= N * NHEAD) return;
    int n = t >> 3, h = t & 7;
    int s = off[n], e = off[n + 1];
    float ad = adst[(size_t)n * NHEAD + h];
    float m = -INFINITY;
    for (int j = s; j < e; j++) {
        float v = asrc[(size_t)ssrc[j] * NHEAD + h] + ad;
        v = (v > 0.f) ? v : NEG_SLOPE * v;
        m = fmaxf(m, v);
    }
    float sum = 0.f;
    for (int j = s; j < e; j++) {
        float v = asrc[(size_t)ssrc[j] * NHEAD + h] + ad;
        v = (v > 0.f) ? v : NEG_SLOPE * v;
        float ex = __expf(v - m);
        p[(size_t)j * NHEAD + h] = ex;
        sum += ex;
    }
    float inv = 1.0f / sum;
    for (int j = s; j < e; j++) p[(size_t)j * NHEAD + h] *= inv;
}

// ---------------- aggregation + BN + ReLU (+pool on last layer) ----------------
__global__ __launch_bounds__(320) void aggregate(
    const short* __restrict__ xh_bf, const float* __restrict__ p,
    const int* __restrict__ off, const int* __restrict__ ssrc,
    const float* __restrict__ prev_f,     // fp32 residual (layer 1: x) or null
    const short* __restrict__ prev_bf,    // bf16 residual (layer 2: hA_bf) or null
    const float* __restrict__ b_att, const float* __restrict__ gamma,
    const float* __restrict__ beta, const float* __restrict__ mean,
    const float* __restrict__ var,
    short* __restrict__ hout_bf,          // bf16 h for next layer (null on last)
    float* __restrict__ pooled, const int* __restrict__ batch, int N) {
    int n = blockIdx.x;
    int t = threadIdx.x;
    if (t >= 260) return;
    int f0 = t * 4;
    int s = off[n], e = off[n + 1];
    int hh[4];
#pragma unroll
    for (int i = 0; i < 4; i++) hh[i] = (f0 + i) / DHEAD;
    float acc[4] = {0.f, 0.f, 0.f, 0.f};
    for (int j = s; j < e; j++) {
        int src = ssrc[j];
        ushort4 v = *(const ushort4*)(xh_bf + (size_t)src * FEAT + f0);
        const float* pj = p + (size_t)j * NHEAD;
        acc[0] += pj[hh[0]] * bf2f((short)v.x);
        acc[1] += pj[hh[1]] * bf2f((short)v.y);
        acc[2] += pj[hh[2]] * bf2f((short)v.z);
        acc[3] += pj[hh[3]] * bf2f((short)v.w);
    }
    float4 bv = *(const float4*)(b_att + f0);
    float4 gv = *(const float4*)(gamma + f0);
    float4 be = *(const float4*)(beta + f0);
    float4 mv = *(const float4*)(mean + f0);
    float4 vv = *(const float4*)(var + f0);
    float z[4] = {acc[0] + bv.x, acc[1] + bv.y, acc[2] + bv.z, acc[3] + bv.w};
    if (prev_f) {
        float4 pv = *(const float4*)(prev_f + (size_t)n * FEAT + f0);
        z[0] += pv.x; z[1] += pv.y; z[2] += pv.z; z[3] += pv.w;
    }
    if (prev_bf) {
        ushort4 pv = *(const ushort4*)(prev_bf + (size_t)n * KP + f0);
        z[0] += bf2f((short)pv.x); z[1] += bf2f((short)pv.y);
        z[2] += bf2f((short)pv.z); z[3] += bf2f((short)pv.w);
    }
    float g4[4] = {gv.x, gv.y, gv.z, gv.w};
    float b4[4] = {be.x, be.y, be.z, be.w};
    float m4[4] = {mv.x, mv.y, mv.z, mv.w};
    float v4[4] = {vv.x, vv.y, vv.z, vv.w};
    float hn[4];
#pragma unroll
    for (int i = 0; i < 4; i++) {
        float zz = (z[i] - m4[i]) * rsqrtf(v4[i] + BN_EPS) * g4[i] + b4[i];
        hn[i] = fmaxf(zz, 0.f);
    }
    if (hout_bf) {
        ushort4 o;
        o.x = (unsigned short)f2bf(hn[0]);
        o.y = (unsigned short)f2bf(hn[1]);
        o.z = (unsigned short)f2bf(hn[2]);
        o.w = (unsigned short)f2bf(hn[3]);
        *(ushort4*)(hout_bf + (size_t)n * KP + f0) = o;
    } else {
        float* pg = pooled + (size_t)batch[n] * FEAT + f0;
#pragma unroll
        for (int i = 0; i < 4; i++) atomicAdd(&pg[i], hn[i]);
    }
}

__global__ void final_k(const float* __restrict__ pooled, const float* __restrict__ counts,
                        const float* __restrict__ W_out, const float* __restrict__ b_out,
                        float* __restrict__ out) {
    int g = blockIdx.x >> 1, c = blockIdx.x & 1;
    int lane = threadIdx.x;  // 64
    float ssum = 0.f;
    for (int f = lane; f < FEAT; f += 64) ssum += pooled[(size_t)g * FEAT + f] * W_out[f * 2 + c];
#pragma unroll
    for (int o = 1; o < 64; o <<= 1) ssum += __shfl_xor(ssum, o);
    if (lane == 0) {
        float inv = 1.0f / fmaxf(counts[g], 1.0f);
        out[g * 2 + c] = ssum * inv + b_out[c];
    }
}

// ---------------- launch ----------------
extern "C" void kernel_launch(void* const* d_in, const int* in_sizes, int n_in,
                              void* d_out, int out_size, void* d_ws, size_t ws_size,
                              hipStream_t stream) {
    const float* x       = (const float*)d_in[0];
    const int*   ei      = (const int*)d_in[1];
    const int*   batch   = (const int*)d_in[2];
    const float* W       = (const float*)d_in[3];
    const float* a_src   = (const float*)d_in[4];
    const float* a_dst   = (const float*)d_in[5];
    const float* b_att   = (const float*)d_in[6];
    const float* gamma   = (const float*)d_in[7];
    const float* beta    = (const float*)d_in[8];
    const float* r_mean  = (const float*)d_in[9];
    const float* r_var   = (const float*)d_in[10];
    const float* W_out   = (const float*)d_in[11];
    const float* b_out   = (const float*)d_in[12];
    float* out = (float*)d_out;

    const int N = in_sizes[0] / FEAT;
    const int E = in_sizes[1] / 2;
    const int E2 = E + N;
    const int MT = (N + 127) / 128;
    const int Mp = MT * 128;

    char* w = (char*)d_ws;
    auto alloc = [&](size_t bytes) {
        void* pp = (void*)w;
        w += (bytes + 255) & ~(size_t)255;
        return pp;
    };
    short* xh_bf  = (short*)alloc((size_t)N * FEAT * 2);        // GEMM out (bf16)
    short* x_bf   = (short*)alloc((size_t)Mp * KP * 2);
    short* hA_bf  = (short*)alloc((size_t)Mp * KP * 2);
    short* hB_bf  = (short*)alloc((size_t)Mp * KP * 2);
    short* Bt3    = (short*)alloc((size_t)NLAYER * NP * KP * 2);
    float* p      = (float*)alloc((size_t)E2 * NHEAD * 4);
    float* asrc   = (float*)alloc((size_t)N * NHEAD * 4);
    float* adst   = (float*)alloc((size_t)N * NHEAD * 4);
    int*   src2   = (int*)alloc((size_t)E2 * 4);
    int*   dst2   = (int*)alloc((size_t)E2 * 4);
    int*   ssrc   = (int*)alloc((size_t)E2 * 4);
    int*   sdst   = (int*)alloc((size_t)E2 * 4);
    int*   deg    = (int*)alloc((size_t)N * 4);
    int*   off    = (int*)alloc((size_t)(N + 1) * 4);
    int*   cursor = (int*)alloc((size_t)N * 4);
    float* pooled = (float*)alloc((size_t)NGRAPH * FEAT * 4);
    float* counts = (float*)alloc((size_t)NGRAPH * 4);

    hipMemsetAsync(deg, 0, (size_t)N * 4, stream);
    hipMemsetAsync(pooled, 0, (size_t)NGRAPH * FEAT * 4, stream);
    hipMemsetAsync(counts, 0, (size_t)NGRAPH * 4, stream);
    hipMemsetAsync(Bt3, 0, (size_t)NLAYER * NP * KP * 2, stream);

    conv_x_bf<<<(N * FEAT + 255) / 256, 256, 0, stream>>>(x, x_bf, N);
    pad_bf<<<Mp, 64, 0, stream>>>(x_bf, N);
    pad_bf<<<Mp, 64, 0, stream>>>(hA_bf, N);
    pad_bf<<<Mp, 64, 0, stream>>>(hB_bf, N);
    dim3 tgrid((FEAT + 31) / 32, (FEAT + 31) / 32);
    for (int l = 0; l < NLAYER; l++)
        transpose_w<<<tgrid, 256, 0, stream>>>(W + (size_t)l * FEAT * FEAT,
                                               Bt3 + (size_t)l * NP * KP);
    wa_kernel<<<(NLAYER * FEAT * NHEAD + 255) / 256, 256, 0, stream>>>(W, a_src, a_dst, Bt3);

    build_edges<<<(E2 + 255) / 256, 256, 0, stream>>>(ei, E, N, src2, dst2, deg);
    scan_kernel<<<1, 1024, 0, stream>>>(deg, off, cursor, N);
    scatter_k<<<(E2 + 255) / 256, 256, 0, stream>>>(src2, dst2, cursor, ssrc, sdst, E2);
    count_k<<<(N + 255) / 256, 256, 0, stream>>>(batch, counts, N);

    const short* hin[NLAYER]     = {x_bf, hA_bf, hB_bf};
    const float* prevf[NLAYER]   = {nullptr, x, nullptr};
    const short* prevbf[NLAYER]  = {nullptr, nullptr, hA_bf};
    short* houtl[NLAYER]         = {hA_bf, hB_bf, nullptr};

    dim3 ggrid(NP / 128, MT);
    for (int l = 0; l < NLAYER; l++) {
        gemm_mfma<<<ggrid, 256, 0, stream>>>(hin[l], Bt3 + (size_t)l * NP * KP,
                                             xh_bf, asrc, adst, N);
        att_softmax<<<(N * NHEAD + 255) / 256, 256, 0, stream>>>(off, ssrc, asrc, adst, p, N);
        aggregate<<<N, 320, 0, stream>>>(xh_bf, p, off, ssrc, prevf[l], prevbf[l],
                                         b_att + l * FEAT, gamma + l * FEAT, beta + l * FEAT,
                                         r_mean + l * FEAT, r_var + l * FEAT,
                                         houtl[l], pooled, batch, N);
    }

    final_k<<<NGRAPH * 2, 64, 0, stream>>>(pooled, counts, W_out, b_out, out);
}

// Round 4
// 1312.401 us; speedup vs baseline: 3.2288x; 1.5544x over previous
//
#include <hip/hip_runtime.h>
#include <hip/hip_bf16.h>
#include <math.h>

#define FEAT 1040
#define NHEAD 8
#define DHEAD 130
#define NLAYER 3
#define NGRAPH 64
#define NEG_SLOPE 0.2f
#define BN_EPS 1e-5f
#define KP 1056   // FEAT padded to multiple of 32 (K of GEMM)
#define NP 1152   // FEAT padded to multiple of 128 (N of GEMM); cols 1040..1055 = wa_src/wa_dst

typedef float floatx4 __attribute__((ext_vector_type(4)));
typedef short shortx8 __attribute__((ext_vector_type(8)));

__device__ __forceinline__ short f2bf(float f) {
    unsigned u = __float_as_uint(f);
    u += 0x7fff + ((u >> 16) & 1);   // round-to-nearest-even
    return (short)(u >> 16);
}
__device__ __forceinline__ float bf2f(short b) {
    return __uint_as_float(((unsigned)(unsigned short)b) << 16);
}

__device__ __forceinline__ void async16(const void* g, void* l) {
    __builtin_amdgcn_global_load_lds(
        (const __attribute__((address_space(1))) unsigned int*)g,
        (__attribute__((address_space(3))) unsigned int*)l, 16, 0, 0);
}

// ---------------- bf16 MFMA GEMM ----------------
__global__ __launch_bounds__(256) void gemm_mfma(const short* __restrict__ A,
                                                 const short* __restrict__ Bt,
                                                 short* __restrict__ xh_bf,
                                                 float* __restrict__ asrc,
                                                 float* __restrict__ adst,
                                                 int M) {
    __shared__ short As[128 * 32];
    __shared__ short Bs[128 * 32];
    const int tid = threadIdx.x;
    const int lane = tid & 63;
    const int w = tid >> 6;
    const int wm = (w & 1) * 64;
    const int wn = (w >> 1) * 64;
    const int bm = blockIdx.y * 128;
    const int bn = blockIdx.x * 128;

    const int tt0 = tid, tt1 = 256 + tid;
    const int row0 = ((tt0 >> 6) << 4) | (tt0 & 15);
    const int col0 = ((tt0 >> 4) & 3) * 8;
    const int row1 = ((tt1 >> 6) << 4) | (tt1 & 15);
    const int col1 = ((tt1 >> 4) & 3) * 8;

    const short* gA0 = A + (size_t)(bm + row0) * KP + col0;
    const short* gA1 = A + (size_t)(bm + row1) * KP + col1;
    const short* gB0 = Bt + (size_t)(bn + row0) * KP + col0;
    const short* gB1 = Bt + (size_t)(bn + row1) * KP + col1;
    short* lA0 = &As[tt0 * 8];
    short* lA1 = &As[tt1 * 8];
    short* lB0 = &Bs[tt0 * 8];
    short* lB1 = &Bs[tt1 * 8];

    const int fr = lane & 15;
    const int kq = lane >> 4;

    floatx4 acc[4][4];
#pragma unroll
    for (int i = 0; i < 4; i++)
#pragma unroll
        for (int j = 0; j < 4; j++) acc[i][j] = (floatx4){0.f, 0.f, 0.f, 0.f};

    for (int k0 = 0; k0 < KP; k0 += 32) {
        async16(gA0 + k0, lA0);
        async16(gA1 + k0, lA1);
        async16(gB0 + k0, lB0);
        async16(gB1 + k0, lB1);
        __syncthreads();

        shortx8 af[4], bfr[4];
#pragma unroll
        for (int i = 0; i < 4; i++) {
            af[i]  = *(const shortx8*)&As[((wm >> 4) + i) * 512 + kq * 128 + fr * 8];
            bfr[i] = *(const shortx8*)&Bs[((wn >> 4) + i) * 512 + kq * 128 + fr * 8];
        }
#pragma unroll
        for (int i = 0; i < 4; i++)
#pragma unroll
            for (int j = 0; j < 4; j++)
                acc[i][j] = __builtin_amdgcn_mfma_f32_16x16x32_bf16(af[i], bfr[j], acc[i][j], 0, 0, 0);
        __syncthreads();
    }

    const int rbase = (lane >> 4) * 4;
    const int ccol = lane & 15;
#pragma unroll
    for (int j = 0; j < 4; j++) {
        int colbase = bn + wn + j * 16;
        if (colbase < FEAT) {
            int col = colbase + ccol;
#pragma unroll
            for (int i = 0; i < 4; i++)
#pragma unroll
                for (int r = 0; r < 4; r++) {
                    int row = bm + wm + i * 16 + rbase + r;
                    if (row < M) xh_bf[(size_t)row * FEAT + col] = f2bf(acc[i][j][r]);
                }
        } else if (colbase == FEAT) {
            int c = ccol;
            float* tgt = (c < 8) ? asrc : adst;
            int h = c & 7;
#pragma unroll
            for (int i = 0; i < 4; i++)
#pragma unroll
                for (int r = 0; r < 4; r++) {
                    int row = bm + wm + i * 16 + rbase + r;
                    if (row < M) tgt[(size_t)row * NHEAD + h] = acc[i][j][r];
                }
        }
    }
}

// ---------------- conversions / padding ----------------
__global__ void conv_x_bf(const float* __restrict__ x, short* __restrict__ out, int N) {
    int idx = blockIdx.x * 256 + threadIdx.x;
    if (idx >= N * FEAT) return;
    int r = idx / FEAT, c = idx - r * FEAT;
    out[(size_t)r * KP + c] = f2bf(x[idx]);
}

__global__ void pad_bf(short* __restrict__ buf, int Mvalid) {
    int r = blockIdx.x;
    short* row = buf + (size_t)r * KP;
    if (r < Mvalid) {
        if (threadIdx.x < KP - FEAT) row[FEAT + threadIdx.x] = 0;
    } else {
        for (int c = threadIdx.x; c < KP; c += 64) row[c] = 0;
    }
}

__global__ void transpose_w(const float* __restrict__ Wl, short* __restrict__ Bt) {
    __shared__ float t[32][33];
    int kb = blockIdx.x * 32, nb = blockIdx.y * 32;
    int tx = threadIdx.x & 31, ty = threadIdx.x >> 5;
#pragma unroll
    for (int i = 0; i < 4; i++) {
        int k = kb + ty + i * 8, n = nb + tx;
        t[ty + i * 8][tx] = (k < FEAT && n < FEAT) ? Wl[(size_t)k * FEAT + n] : 0.f;
    }
    __syncthreads();
#pragma unroll
    for (int i = 0; i < 4; i++) {
        int n = nb + ty + i * 8, k = kb + tx;
        if (n < FEAT && k < FEAT) Bt[(size_t)n * KP + k] = f2bf(t[tx][ty + i * 8]);
    }
}

__global__ void wa_kernel(const float* __restrict__ W, const float* __restrict__ a_s,
                          const float* __restrict__ a_d, short* __restrict__ Bt3) {
    int t = blockIdx.x * 256 + threadIdx.x;
    if (t >= NLAYER * FEAT * NHEAD) return;
    int h = t & 7;
    int f = (t >> 3) % FEAT;
    int l = t / (FEAT * NHEAD);
    const float* wrow = W + (((size_t)l * FEAT + f) * NHEAD + h) * DHEAD;
    const float* as = a_s + ((size_t)l * NHEAD + h) * DHEAD;
    const float* ad = a_d + ((size_t)l * NHEAD + h) * DHEAD;
    float ws = 0.f, wd = 0.f;
    for (int d = 0; d < DHEAD; d++) {
        float wv = wrow[d];
        ws += wv * as[d];
        wd += wv * ad[d];
    }
    short* base = Bt3 + (size_t)l * NP * KP;
    base[(size_t)(FEAT + h) * KP + f] = f2bf(ws);
    base[(size_t)(FEAT + 8 + h) * KP + f] = f2bf(wd);
}

// ---------------- graph preprocessing ----------------
__global__ void build_edges(const int* __restrict__ ei, int E, int N,
                            int* __restrict__ src2, int* __restrict__ dst2,
                            int* __restrict__ deg) {
    int e = blockIdx.x * 256 + threadIdx.x;
    int E2 = E + N;
    if (e >= E2) return;
    int s, d;
    if (e < E) { s = ei[e]; d = ei[E + e]; }
    else       { s = e - E; d = e - E; }
    src2[e] = s;
    dst2[e] = d;
    atomicAdd(&deg[d], 1);
}

__global__ void scan_kernel(const int* __restrict__ deg, int* __restrict__ off,
                            int* __restrict__ cursor, int N) {
    __shared__ int wsum[16];
    __shared__ int carry_s;
    int tid = threadIdx.x;
    int lane = tid & 63, wid = tid >> 6;
    if (tid == 0) carry_s = 0;
    __syncthreads();
    for (int base = 0; base < N; base += 1024) {
        int i = base + tid;
        int v = (i < N) ? deg[i] : 0;
        int incl = v;
#pragma unroll
        for (int o = 1; o < 64; o <<= 1) {
            int u = __shfl_up(incl, o);
            if (lane >= o) incl += u;
        }
        if (lane == 63) wsum[wid] = incl;
        __syncthreads();
        if (wid == 0) {
            int wv = (lane < 16) ? wsum[lane] : 0;
            int wincl = wv;
#pragma unroll
            for (int o = 1; o < 16; o <<= 1) {
                int u = __shfl_up(wincl, o);
                if (lane >= o) wincl += u;
            }
            if (lane < 16) wsum[lane] = wincl - wv;
        }
        __syncthreads();
        int excl = carry_s + wsum[wid] + incl - v;
        if (i < N) { off[i] = excl; cursor[i] = excl; }
        int tot = 0;
        if (tid == 1023) tot = wsum[15] + incl;
        __syncthreads();
        if (tid == 1023) carry_s += tot;
        __syncthreads();
    }
    if (threadIdx.x == 0) off[N] = carry_s;
}

__global__ void scatter_k(const int* __restrict__ src2, const int* __restrict__ dst2,
                          int* __restrict__ cursor, int* __restrict__ ssrc,
                          int* __restrict__ sdst, int E2) {
    int e = blockIdx.x * 256 + threadIdx.x;
    if (e >= E2) return;
    int d = dst2[e];
    int pos = atomicAdd(&cursor[d], 1);
    ssrc[pos] = src2[e];
    sdst[pos] = d;
}

// batch is sorted: graph g occupies nodes [gstart[g], gstart[g+1])
__global__ void gstart_k(const int* __restrict__ batch, int* __restrict__ gstart, int N) {
    int n = blockIdx.x * 256 + threadIdx.x;
    if (n >= N) return;
    int b = batch[n];
    if (n == 0) {
        for (int g = 0; g <= b; g++) gstart[g] = 0;
    } else {
        int pb = batch[n - 1];
        for (int g = pb + 1; g <= b; g++) gstart[g] = n;
    }
    if (n == N - 1) {
        for (int g = b + 1; g <= NGRAPH; g++) gstart[g] = N;
    }
}

// ---------------- fused leaky-relu + segment softmax ----------------
__global__ void att_softmax(const int* __restrict__ off, const int* __restrict__ ssrc,
                            const float* __restrict__ asrc, const float* __restrict__ adst,
                            float* __restrict__ p, int N) {
    int t = blockIdx.x * 256 + threadIdx.x;
    if (t >= N * NHEAD) return;
    int n = t >> 3, h = t & 7;
    int s = off[n], e = off[n + 1];
    float ad = adst[(size_t)n * NHEAD + h];
    float m = -INFINITY;
    for (int j = s; j < e; j++) {
        float v = asrc[(size_t)ssrc[j] * NHEAD + h] + ad;
        v = (v > 0.f) ? v : NEG_SLOPE * v;
        m = fmaxf(m, v);
    }
    float sum = 0.f;
    for (int j = s; j < e; j++) {
        float v = asrc[(size_t)ssrc[j] * NHEAD + h] + ad;
        v = (v > 0.f) ? v : NEG_SLOPE * v;
        float ex = __expf(v - m);
        p[(size_t)j * NHEAD + h] = ex;
        sum += ex;
    }
    float inv = 1.0f / sum;
    for (int j = s; j < e; j++) p[(size_t)j * NHEAD + h] *= inv;
}

// ---------------- aggregation + BN + ReLU (always writes bf16 h) ----------------
__global__ __launch_bounds__(320) void aggregate(
    const short* __restrict__ xh_bf, const float* __restrict__ p,
    const int* __restrict__ off, const int* __restrict__ ssrc,
    const float* __restrict__ prev_f,     // fp32 residual (layer 1: x) or null
    const short* __restrict__ prev_bf,    // bf16 residual (layer 2: hA_bf) or null
    const float* __restrict__ b_att, const float* __restrict__ gamma,
    const float* __restrict__ beta, const float* __restrict__ mean,
    const float* __restrict__ var,
    short* __restrict__ hout_bf, int N) {
    int n = blockIdx.x;
    int t = threadIdx.x;
    if (t >= 260) return;
    int f0 = t * 4;
    int s = off[n], e = off[n + 1];
    int hh[4];
#pragma unroll
    for (int i = 0; i < 4; i++) hh[i] = (f0 + i) / DHEAD;
    float acc[4] = {0.f, 0.f, 0.f, 0.f};

    int j = s;
    // unrolled x4: 4 outstanding gathers
    for (; j + 4 <= e; j += 4) {
        int s0 = ssrc[j], s1 = ssrc[j + 1], s2 = ssrc[j + 2], s3 = ssrc[j + 3];
        ushort4 v0 = *(const ushort4*)(xh_bf + (size_t)s0 * FEAT + f0);
        ushort4 v1 = *(const ushort4*)(xh_bf + (size_t)s1 * FEAT + f0);
        ushort4 v2 = *(const ushort4*)(xh_bf + (size_t)s2 * FEAT + f0);
        ushort4 v3 = *(const ushort4*)(xh_bf + (size_t)s3 * FEAT + f0);
        const float* p0 = p + (size_t)j * NHEAD;
        const float* p1 = p0 + NHEAD;
        const float* p2 = p1 + NHEAD;
        const float* p3 = p2 + NHEAD;
        acc[0] += p0[hh[0]] * bf2f((short)v0.x) + p1[hh[0]] * bf2f((short)v1.x)
                + p2[hh[0]] * bf2f((short)v2.x) + p3[hh[0]] * bf2f((short)v3.x);
        acc[1] += p0[hh[1]] * bf2f((short)v0.y) + p1[hh[1]] * bf2f((short)v1.y)
                + p2[hh[1]] * bf2f((short)v2.y) + p3[hh[1]] * bf2f((short)v3.y);
        acc[2] += p0[hh[2]] * bf2f((short)v0.z) + p1[hh[2]] * bf2f((short)v1.z)
                + p2[hh[2]] * bf2f((short)v2.z) + p3[hh[2]] * bf2f((short)v3.z);
        acc[3] += p0[hh[3]] * bf2f((short)v0.w) + p1[hh[3]] * bf2f((short)v1.w)
                + p2[hh[3]] * bf2f((short)v2.w) + p3[hh[3]] * bf2f((short)v3.w);
    }
    for (; j < e; j++) {
        int src = ssrc[j];
        ushort4 v = *(const ushort4*)(xh_bf + (size_t)src * FEAT + f0);
        const float* pj = p + (size_t)j * NHEAD;
        acc[0] += pj[hh[0]] * bf2f((short)v.x);
        acc[1] += pj[hh[1]] * bf2f((short)v.y);
        acc[2] += pj[hh[2]] * bf2f((short)v.z);
        acc[3] += pj[hh[3]] * bf2f((short)v.w);
    }

    float4 bv = *(const float4*)(b_att + f0);
    float4 gv = *(const float4*)(gamma + f0);
    float4 be = *(const float4*)(beta + f0);
    float4 mv = *(const float4*)(mean + f0);
    float4 vv = *(const float4*)(var + f0);
    float z[4] = {acc[0] + bv.x, acc[1] + bv.y, acc[2] + bv.z, acc[3] + bv.w};
    if (prev_f) {
        float4 pv = *(const float4*)(prev_f + (size_t)n * FEAT + f0);
        z[0] += pv.x; z[1] += pv.y; z[2] += pv.z; z[3] += pv.w;
    }
    if (prev_bf) {
        ushort4 pv = *(const ushort4*)(prev_bf + (size_t)n * KP + f0);
        z[0] += bf2f((short)pv.x); z[1] += bf2f((short)pv.y);
        z[2] += bf2f((short)pv.z); z[3] += bf2f((short)pv.w);
    }
    float g4[4] = {gv.x, gv.y, gv.z, gv.w};
    float b4[4] = {be.x, be.y, be.z, be.w};
    float m4[4] = {mv.x, mv.y, mv.z, mv.w};
    float v4[4] = {vv.x, vv.y, vv.z, vv.w};
    ushort4 o;
    unsigned short* op = (unsigned short*)&o;
#pragma unroll
    for (int i = 0; i < 4; i++) {
        float zz = (z[i] - m4[i]) * rsqrtf(v4[i] + BN_EPS) * g4[i] + b4[i];
        op[i] = (unsigned short)f2bf(fmaxf(zz, 0.f));
    }
    *(ushort4*)(hout_bf + (size_t)n * KP + f0) = o;
}

// ---------------- pooling over contiguous node ranges (no atomics) ----------------
__global__ __launch_bounds__(320) void pool_k(const short* __restrict__ h,
                                              const int* __restrict__ gstart,
                                              float* __restrict__ pooled) {
    int g = blockIdx.x;
    int t = threadIdx.x;
    if (t >= 260) return;
    int f0 = t * 4;
    int s = gstart[g], e = gstart[g + 1];
    float acc[4] = {0.f, 0.f, 0.f, 0.f};
    int n = s;
    for (; n + 4 <= e; n += 4) {
        ushort4 v0 = *(const ushort4*)(h + (size_t)n * KP + f0);
        ushort4 v1 = *(const ushort4*)(h + (size_t)(n + 1) * KP + f0);
        ushort4 v2 = *(const ushort4*)(h + (size_t)(n + 2) * KP + f0);
        ushort4 v3 = *(const ushort4*)(h + (size_t)(n + 3) * KP + f0);
        acc[0] += bf2f((short)v0.x) + bf2f((short)v1.x) + bf2f((short)v2.x) + bf2f((short)v3.x);
        acc[1] += bf2f((short)v0.y) + bf2f((short)v1.y) + bf2f((short)v2.y) + bf2f((short)v3.y);
        acc[2] += bf2f((short)v0.z) + bf2f((short)v1.z) + bf2f((short)v2.z) + bf2f((short)v3.z);
        acc[3] += bf2f((short)v0.w) + bf2f((short)v1.w) + bf2f((short)v2.w) + bf2f((short)v3.w);
    }
    for (; n < e; n++) {
        ushort4 v = *(const ushort4*)(h + (size_t)n * KP + f0);
        acc[0] += bf2f((short)v.x);
        acc[1] += bf2f((short)v.y);
        acc[2] += bf2f((short)v.z);
        acc[3] += bf2f((short)v.w);
    }
    *(float4*)(pooled + (size_t)g * FEAT + f0) = make_float4(acc[0], acc[1], acc[2], acc[3]);
}

__global__ void final_k(const float* __restrict__ pooled, const int* __restrict__ gstart,
                        const float* __restrict__ W_out, const float* __restrict__ b_out,
                        float* __restrict__ out) {
    int g = blockIdx.x >> 1, c = blockIdx.x & 1;
    int lane = threadIdx.x;  // 64
    float ssum = 0.f;
    for (int f = lane; f < FEAT; f += 64) ssum += pooled[(size_t)g * FEAT + f] * W_out[f * 2 + c];
#pragma unroll
    for (int o = 1; o < 64; o <<= 1) ssum += __shfl_xor(ssum, o);
    if (lane == 0) {
        float cnt = (float)(gstart[g + 1] - gstart[g]);
        float inv = 1.0f / fmaxf(cnt, 1.0f);
        out[g * 2 + c] = ssum * inv + b_out[c];
    }
}

// ---------------- launch ----------------
extern "C" void kernel_launch(void* const* d_in, const int* in_sizes, int n_in,
                              void* d_out, int out_size, void* d_ws, size_t ws_size,
                              hipStream_t stream) {
    const float* x       = (const float*)d_in[0];
    const int*   ei      = (const int*)d_in[1];
    const int*   batch   = (const int*)d_in[2];
    const float* W       = (const float*)d_in[3];
    const float* a_src   = (const float*)d_in[4];
    const float* a_dst   = (const float*)d_in[5];
    const float* b_att   = (const float*)d_in[6];
    const float* gamma   = (const float*)d_in[7];
    const float* beta    = (const float*)d_in[8];
    const float* r_mean  = (const float*)d_in[9];
    const float* r_var   = (const float*)d_in[10];
    const float* W_out   = (const float*)d_in[11];
    const float* b_out   = (const float*)d_in[12];
    float* out = (float*)d_out;

    const int N = in_sizes[0] / FEAT;
    const int E = in_sizes[1] / 2;
    const int E2 = E + N;
    const int MT = (N + 127) / 128;
    const int Mp = MT * 128;

    char* w = (char*)d_ws;
    auto alloc = [&](size_t bytes) {
        void* pp = (void*)w;
        w += (bytes + 255) & ~(size_t)255;
        return pp;
    };
    short* xh_bf  = (short*)alloc((size_t)N * FEAT * 2);
    short* x_bf   = (short*)alloc((size_t)Mp * KP * 2);   // layer-0 A; reused as layer-3 h
    short* hA_bf  = (short*)alloc((size_t)Mp * KP * 2);
    short* hB_bf  = (short*)alloc((size_t)Mp * KP * 2);
    short* Bt3    = (short*)alloc((size_t)NLAYER * NP * KP * 2);
    float* p      = (float*)alloc((size_t)E2 * NHEAD * 4);
    float* asrc   = (float*)alloc((size_t)N * NHEAD * 4);
    float* adst   = (float*)alloc((size_t)N * NHEAD * 4);
    int*   src2   = (int*)alloc((size_t)E2 * 4);
    int*   dst2   = (int*)alloc((size_t)E2 * 4);
    int*   ssrc   = (int*)alloc((size_t)E2 * 4);
    int*   sdst   = (int*)alloc((size_t)E2 * 4);
    int*   deg    = (int*)alloc((size_t)N * 4);
    int*   off    = (int*)alloc((size_t)(N + 1) * 4);
    int*   cursor = (int*)alloc((size_t)N * 4);
    int*   gstart = (int*)alloc((size_t)(NGRAPH + 1) * 4);
    float* pooled = (float*)alloc((size_t)NGRAPH * FEAT * 4);

    hipMemsetAsync(deg, 0, (size_t)N * 4, stream);
    hipMemsetAsync(Bt3, 0, (size_t)NLAYER * NP * KP * 2, stream);

    conv_x_bf<<<(N * FEAT + 255) / 256, 256, 0, stream>>>(x, x_bf, N);
    pad_bf<<<Mp, 64, 0, stream>>>(x_bf, N);
    pad_bf<<<Mp, 64, 0, stream>>>(hA_bf, N);
    pad_bf<<<Mp, 64, 0, stream>>>(hB_bf, N);
    dim3 tgrid((FEAT + 31) / 32, (FEAT + 31) / 32);
    for (int l = 0; l < NLAYER; l++)
        transpose_w<<<tgrid, 256, 0, stream>>>(W + (size_t)l * FEAT * FEAT,
                                               Bt3 + (size_t)l * NP * KP);
    wa_kernel<<<(NLAYER * FEAT * NHEAD + 255) / 256, 256, 0, stream>>>(W, a_src, a_dst, Bt3);

    build_edges<<<(E2 + 255) / 256, 256, 0, stream>>>(ei, E, N, src2, dst2, deg);
    scan_kernel<<<1, 1024, 0, stream>>>(deg, off, cursor, N);
    scatter_k<<<(E2 + 255) / 256, 256, 0, stream>>>(src2, dst2, cursor, ssrc, sdst, E2);
    gstart_k<<<(N + 255) / 256, 256, 0, stream>>>(batch, gstart, N);

    const short* hin[NLAYER]     = {x_bf, hA_bf, hB_bf};
    const float* prevf[NLAYER]   = {nullptr, x, nullptr};
    const short* prevbf[NLAYER]  = {nullptr, nullptr, hA_bf};
    short* houtl[NLAYER]         = {hA_bf, hB_bf, x_bf};   // layer-3 h reuses x_bf

    dim3 ggrid(NP / 128, MT);
    for (int l = 0; l < NLAYER; l++) {
        gemm_mfma<<<ggrid, 256, 0, stream>>>(hin[l], Bt3 + (size_t)l * NP * KP,
                                             xh_bf, asrc, adst, N);
        att_softmax<<<(N * NHEAD + 255) / 256, 256, 0, stream>>>(off, ssrc, asrc, adst, p, N);
        aggregate<<<N, 320, 0, stream>>>(xh_bf, p, off, ssrc, prevf[l], prevbf[l],
                                         b_att + l * FEAT, gamma + l * FEAT, beta + l * FEAT,
                                         r_mean + l * FEAT, r_var + l * FEAT,
                                         houtl[l], N);
    }

    pool_k<<<NGRAPH, 320, 0, stream>>>(x_bf, gstart, pooled);
    final_k<<<NGRAPH * 2, 64, 0, stream>>>(pooled, gstart, W_out, b_out, out);
}

// Round 5
// 1140.242 us; speedup vs baseline: 3.7163x; 1.1510x over previous
//
#include <hip/hip_runtime.h>
#include <hip/hip_bf16.h>
#include <math.h>

#define FEAT 1040
#define NHEAD 8
#define DHEAD 130
#define NLAYER 3
#define NGRAPH 64
#define NEG_SLOPE 0.2f
#define BN_EPS 1e-5f
#define KP 1056   // FEAT padded to multiple of 32 (K of GEMM)
#define NP 1152   // FEAT padded to multiple of 128; cols 1040..1055 = wa_src/wa_dst

typedef float floatx4 __attribute__((ext_vector_type(4)));
typedef short shortx8 __attribute__((ext_vector_type(8)));

__device__ __forceinline__ short f2bf(float f) {
    unsigned u = __float_as_uint(f);
    u += 0x7fff + ((u >> 16) & 1);   // round-to-nearest-even
    return (short)(u >> 16);
}
__device__ __forceinline__ float bf2f(short b) {
    return __uint_as_float(((unsigned)(unsigned short)b) << 16);
}

__device__ __forceinline__ void async16(const void* g, void* l) {
    __builtin_amdgcn_global_load_lds(
        (const __attribute__((address_space(1))) unsigned int*)g,
        (__attribute__((address_space(3))) unsigned int*)l, 16, 0, 0);
}

// ---------------- bf16 MFMA GEMM, double-buffered + XCD swizzle ----------------
// 1D grid of MTpad*9 blocks. lid -> (bmi,bni) such that the 9 bni-tiles of one
// bmi land on the same XCD (round-robin id%8) consecutively -> A-slab L2-hot.
__global__ __launch_bounds__(256) void gemm_mfma(const short* __restrict__ A,
                                                 const short* __restrict__ Bt,
                                                 short* __restrict__ xh_bf,
                                                 float* __restrict__ asrc,
                                                 float* __restrict__ adst,
                                                 int M, int MT) {
    const int lid = blockIdx.x;
    const int g = lid / 72, r = lid % 72;
    const int bmi = g * 8 + (r & 7);
    const int bni = r >> 3;
    if (bmi >= MT) return;
    const int bm = bmi * 128;
    const int bn = bni * 128;

    __shared__ short As[2][4096];
    __shared__ short Bs[2][4096];
    const int tid = threadIdx.x;
    const int lane = tid & 63;
    const int w = tid >> 6;
    const int wm = (w & 1) * 64;
    const int wn = (w >> 1) * 64;

    const int tt0 = tid, tt1 = 256 + tid;
    const int row0 = ((tt0 >> 6) << 4) | (tt0 & 15);
    const int col0 = ((tt0 >> 4) & 3) * 8;
    const int row1 = ((tt1 >> 6) << 4) | (tt1 & 15);
    const int col1 = ((tt1 >> 4) & 3) * 8;

    const short* gA0 = A + (size_t)(bm + row0) * KP + col0;
    const short* gA1 = A + (size_t)(bm + row1) * KP + col1;
    const short* gB0 = Bt + (size_t)(bn + row0) * KP + col0;
    const short* gB1 = Bt + (size_t)(bn + row1) * KP + col1;

    const int fr = lane & 15;
    const int kq = lane >> 4;

    floatx4 acc[4][4];
#pragma unroll
    for (int i = 0; i < 4; i++)
#pragma unroll
        for (int j = 0; j < 4; j++) acc[i][j] = (floatx4){0.f, 0.f, 0.f, 0.f};

    // prologue: stage tile 0 into buffer 0
    async16(gA0, &As[0][tt0 * 8]);
    async16(gA1, &As[0][tt1 * 8]);
    async16(gB0, &Bs[0][tt0 * 8]);
    async16(gB1, &Bs[0][tt1 * 8]);
    __syncthreads();

    int cur = 0;
    for (int k0 = 0; k0 < KP; k0 += 32) {
        const int nxt = cur ^ 1;
        const int k1 = k0 + 32;
        if (k1 < KP) {   // prefetch next tile while computing current
            async16(gA0 + k1, &As[nxt][tt0 * 8]);
            async16(gA1 + k1, &As[nxt][tt1 * 8]);
            async16(gB0 + k1, &Bs[nxt][tt0 * 8]);
            async16(gB1 + k1, &Bs[nxt][tt1 * 8]);
        }
        shortx8 af[4], bfr[4];
#pragma unroll
        for (int i = 0; i < 4; i++) {
            af[i]  = *(const shortx8*)&As[cur][((wm >> 4) + i) * 512 + kq * 128 + fr * 8];
            bfr[i] = *(const shortx8*)&Bs[cur][((wn >> 4) + i) * 512 + kq * 128 + fr * 8];
        }
#pragma unroll
        for (int i = 0; i < 4; i++)
#pragma unroll
            for (int j = 0; j < 4; j++)
                acc[i][j] = __builtin_amdgcn_mfma_f32_16x16x32_bf16(af[i], bfr[j], acc[i][j], 0, 0, 0);
        __syncthreads();   // drains prefetch vmcnt + protects buffer reuse
        cur = nxt;
    }

    // C/D layout: col = lane&15, row = (lane>>4)*4 + reg
    const int rbase = (lane >> 4) * 4;
    const int ccol = lane & 15;
#pragma unroll
    for (int j = 0; j < 4; j++) {
        int colbase = bn + wn + j * 16;
        if (colbase < FEAT) {
            int col = colbase + ccol;
#pragma unroll
            for (int i = 0; i < 4; i++)
#pragma unroll
                for (int r2 = 0; r2 < 4; r2++) {
                    int row = bm + wm + i * 16 + rbase + r2;
                    if (row < M) xh_bf[(size_t)row * FEAT + col] = f2bf(acc[i][j][r2]);
                }
        } else if (colbase == FEAT) {
            int c = ccol;
            float* tgt = (c < 8) ? asrc : adst;
            int h = c & 7;
#pragma unroll
            for (int i = 0; i < 4; i++)
#pragma unroll
                for (int r2 = 0; r2 < 4; r2++) {
                    int row = bm + wm + i * 16 + rbase + r2;
                    if (row < M) tgt[(size_t)row * NHEAD + h] = acc[i][j][r2];
                }
        }
    }
}

// ---------------- conversions / padding ----------------
__global__ void conv_x_bf(const float* __restrict__ x, short* __restrict__ out, int N) {
    int idx = blockIdx.x * 256 + threadIdx.x;
    if (idx >= N * FEAT) return;
    int r = idx / FEAT, c = idx - r * FEAT;
    out[(size_t)r * KP + c] = f2bf(x[idx]);
}

__global__ void pad_bf(short* __restrict__ buf, int Mvalid) {
    int r = blockIdx.x;
    short* row = buf + (size_t)r * KP;
    if (r < Mvalid) {
        if (threadIdx.x < KP - FEAT) row[FEAT + threadIdx.x] = 0;
    } else {
        for (int c = threadIdx.x; c < KP; c += 64) row[c] = 0;
    }
}

__global__ void transpose_w(const float* __restrict__ Wl, short* __restrict__ Bt) {
    __shared__ float t[32][33];
    int kb = blockIdx.x * 32, nb = blockIdx.y * 32;
    int tx = threadIdx.x & 31, ty = threadIdx.x >> 5;
#pragma unroll
    for (int i = 0; i < 4; i++) {
        int k = kb + ty + i * 8, n = nb + tx;
        t[ty + i * 8][tx] = (k < FEAT && n < FEAT) ? Wl[(size_t)k * FEAT + n] : 0.f;
    }
    __syncthreads();
#pragma unroll
    for (int i = 0; i < 4; i++) {
        int n = nb + ty + i * 8, k = kb + tx;
        if (n < FEAT && k < FEAT) Bt[(size_t)n * KP + k] = f2bf(t[tx][ty + i * 8]);
    }
}

__global__ void wa_kernel(const float* __restrict__ W, const float* __restrict__ a_s,
                          const float* __restrict__ a_d, short* __restrict__ Bt3) {
    int t = blockIdx.x * 256 + threadIdx.x;
    if (t >= NLAYER * FEAT * NHEAD) return;
    int h = t & 7;
    int f = (t >> 3) % FEAT;
    int l = t / (FEAT * NHEAD);
    const float* wrow = W + (((size_t)l * FEAT + f) * NHEAD + h) * DHEAD;
    const float* as = a_s + ((size_t)l * NHEAD + h) * DHEAD;
    const float* ad = a_d + ((size_t)l * NHEAD + h) * DHEAD;
    float ws = 0.f, wd = 0.f;
    for (int d = 0; d < DHEAD; d++) {
        float wv = wrow[d];
        ws += wv * as[d];
        wd += wv * ad[d];
    }
    short* base = Bt3 + (size_t)l * NP * KP;
    base[(size_t)(FEAT + h) * KP + f] = f2bf(ws);
    base[(size_t)(FEAT + 8 + h) * KP + f] = f2bf(wd);
}

// ---------------- graph preprocessing ----------------
__global__ void build_edges(const int* __restrict__ ei, int E, int N,
                            int* __restrict__ src2, int* __restrict__ dst2,
                            int* __restrict__ deg) {
    int e = blockIdx.x * 256 + threadIdx.x;
    int E2 = E + N;
    if (e >= E2) return;
    int s, d;
    if (e < E) { s = ei[e]; d = ei[E + e]; }
    else       { s = e - E; d = e - E; }
    src2[e] = s;
    dst2[e] = d;
    atomicAdd(&deg[d], 1);
}

__global__ void scan_kernel(const int* __restrict__ deg, int* __restrict__ off,
                            int* __restrict__ cursor, int N) {
    __shared__ int wsum[16];
    __shared__ int carry_s;
    int tid = threadIdx.x;
    int lane = tid & 63, wid = tid >> 6;
    if (tid == 0) carry_s = 0;
    __syncthreads();
    for (int base = 0; base < N; base += 1024) {
        int i = base + tid;
        int v = (i < N) ? deg[i] : 0;
        int incl = v;
#pragma unroll
        for (int o = 1; o < 64; o <<= 1) {
            int u = __shfl_up(incl, o);
            if (lane >= o) incl += u;
        }
        if (lane == 63) wsum[wid] = incl;
        __syncthreads();
        if (wid == 0) {
            int wv = (lane < 16) ? wsum[lane] : 0;
            int wincl = wv;
#pragma unroll
            for (int o = 1; o < 16; o <<= 1) {
                int u = __shfl_up(wincl, o);
                if (lane >= o) wincl += u;
            }
            if (lane < 16) wsum[lane] = wincl - wv;
        }
        __syncthreads();
        int excl = carry_s + wsum[wid] + incl - v;
        if (i < N) { off[i] = excl; cursor[i] = excl; }
        int tot = 0;
        if (tid == 1023) tot = wsum[15] + incl;
        __syncthreads();
        if (tid == 1023) carry_s += tot;
        __syncthreads();
    }
    if (threadIdx.x == 0) off[N] = carry_s;
}

__global__ void scatter_k(const int* __restrict__ src2, const int* __restrict__ dst2,
                          int* __restrict__ cursor, int* __restrict__ ssrc,
                          int* __restrict__ sdst, int E2) {
    int e = blockIdx.x * 256 + threadIdx.x;
    if (e >= E2) return;
    int d = dst2[e];
    int pos = atomicAdd(&cursor[d], 1);
    ssrc[pos] = src2[e];
    sdst[pos] = d;
}

__global__ void gstart_k(const int* __restrict__ batch, int* __restrict__ gstart, int N) {
    int n = blockIdx.x * 256 + threadIdx.x;
    if (n >= N) return;
    int b = batch[n];
    if (n == 0) {
        for (int g = 0; g <= b; g++) gstart[g] = 0;
    } else {
        int pb = batch[n - 1];
        for (int g = pb + 1; g <= b; g++) gstart[g] = n;
    }
    if (n == N - 1) {
        for (int g = b + 1; g <= NGRAPH; g++) gstart[g] = N;
    }
}

// ---------------- leaky-relu + segment softmax (unnormalized; denom_inv out) --
__global__ void att_softmax(const int* __restrict__ off, const int* __restrict__ ssrc,
                            const float* __restrict__ asrc, const float* __restrict__ adst,
                            float* __restrict__ p, float* __restrict__ dinv, int N) {
    int t = blockIdx.x * 256 + threadIdx.x;
    if (t >= N * NHEAD) return;
    int n = t >> 3, h = t & 7;
    int s = off[n], e = off[n + 1];
    float ad = adst[(size_t)n * NHEAD + h];
    float m = -INFINITY;
    int j = s;
    for (; j + 4 <= e; j += 4) {
        float v0 = asrc[(size_t)ssrc[j] * NHEAD + h] + ad;
        float v1 = asrc[(size_t)ssrc[j + 1] * NHEAD + h] + ad;
        float v2 = asrc[(size_t)ssrc[j + 2] * NHEAD + h] + ad;
        float v3 = asrc[(size_t)ssrc[j + 3] * NHEAD + h] + ad;
        v0 = (v0 > 0.f) ? v0 : NEG_SLOPE * v0;
        v1 = (v1 > 0.f) ? v1 : NEG_SLOPE * v1;
        v2 = (v2 > 0.f) ? v2 : NEG_SLOPE * v2;
        v3 = (v3 > 0.f) ? v3 : NEG_SLOPE * v3;
        m = fmaxf(m, fmaxf(fmaxf(v0, v1), fmaxf(v2, v3)));
    }
    for (; j < e; j++) {
        float v = asrc[(size_t)ssrc[j] * NHEAD + h] + ad;
        v = (v > 0.f) ? v : NEG_SLOPE * v;
        m = fmaxf(m, v);
    }
    float sum = 0.f;
    for (j = s; j + 4 <= e; j += 4) {
        float v0 = asrc[(size_t)ssrc[j] * NHEAD + h] + ad;
        float v1 = asrc[(size_t)ssrc[j + 1] * NHEAD + h] + ad;
        float v2 = asrc[(size_t)ssrc[j + 2] * NHEAD + h] + ad;
        float v3 = asrc[(size_t)ssrc[j + 3] * NHEAD + h] + ad;
        v0 = (v0 > 0.f) ? v0 : NEG_SLOPE * v0;
        v1 = (v1 > 0.f) ? v1 : NEG_SLOPE * v1;
        v2 = (v2 > 0.f) ? v2 : NEG_SLOPE * v2;
        v3 = (v3 > 0.f) ? v3 : NEG_SLOPE * v3;
        float e0 = __expf(v0 - m), e1 = __expf(v1 - m);
        float e2 = __expf(v2 - m), e3 = __expf(v3 - m);
        p[(size_t)j * NHEAD + h] = e0;
        p[(size_t)(j + 1) * NHEAD + h] = e1;
        p[(size_t)(j + 2) * NHEAD + h] = e2;
        p[(size_t)(j + 3) * NHEAD + h] = e3;
        sum += (e0 + e1) + (e2 + e3);
    }
    for (; j < e; j++) {
        float v = asrc[(size_t)ssrc[j] * NHEAD + h] + ad;
        v = (v > 0.f) ? v : NEG_SLOPE * v;
        float ex = __expf(v - m);
        p[(size_t)j * NHEAD + h] = ex;
        sum += ex;
    }
    dinv[(size_t)n * NHEAD + h] = 1.0f / sum;
}

// ---------------- aggregation + BN + ReLU (softmax denom folded in) ----------
__global__ __launch_bounds__(320) void aggregate(
    const short* __restrict__ xh_bf, const float* __restrict__ p,
    const float* __restrict__ dinv,
    const int* __restrict__ off, const int* __restrict__ ssrc,
    const float* __restrict__ prev_f,     // fp32 residual (layer 1: x) or null
    const short* __restrict__ prev_bf,    // bf16 residual (layer 2: hA_bf) or null
    const float* __restrict__ b_att, const float* __restrict__ gamma,
    const float* __restrict__ beta, const float* __restrict__ mean,
    const float* __restrict__ var,
    short* __restrict__ hout_bf, int N) {
    int n = blockIdx.x;
    int t = threadIdx.x;
    if (t >= 260) return;
    int f0 = t * 4;
    int s = off[n], e = off[n + 1];
    int hh[4];
#pragma unroll
    for (int i = 0; i < 4; i++) hh[i] = (f0 + i) / DHEAD;
    float acc[4] = {0.f, 0.f, 0.f, 0.f};

    int j = s;
    for (; j + 8 <= e; j += 8) {
        int sj[8];
        ushort4 v[8];
#pragma unroll
        for (int u = 0; u < 8; u++) sj[u] = ssrc[j + u];
#pragma unroll
        for (int u = 0; u < 8; u++) v[u] = *(const ushort4*)(xh_bf + (size_t)sj[u] * FEAT + f0);
#pragma unroll
        for (int u = 0; u < 8; u++) {
            const float* pj = p + (size_t)(j + u) * NHEAD;
            acc[0] += pj[hh[0]] * bf2f((short)v[u].x);
            acc[1] += pj[hh[1]] * bf2f((short)v[u].y);
            acc[2] += pj[hh[2]] * bf2f((short)v[u].z);
            acc[3] += pj[hh[3]] * bf2f((short)v[u].w);
        }
    }
    for (; j + 4 <= e; j += 4) {
        int s0 = ssrc[j], s1 = ssrc[j + 1], s2 = ssrc[j + 2], s3 = ssrc[j + 3];
        ushort4 v0 = *(const ushort4*)(xh_bf + (size_t)s0 * FEAT + f0);
        ushort4 v1 = *(const ushort4*)(xh_bf + (size_t)s1 * FEAT + f0);
        ushort4 v2 = *(const ushort4*)(xh_bf + (size_t)s2 * FEAT + f0);
        ushort4 v3 = *(const ushort4*)(xh_bf + (size_t)s3 * FEAT + f0);
        const float* p0 = p + (size_t)j * NHEAD;
        const float* p1 = p0 + NHEAD;
        const float* p2 = p1 + NHEAD;
        const float* p3 = p2 + NHEAD;
        acc[0] += p0[hh[0]] * bf2f((short)v0.x) + p1[hh[0]] * bf2f((short)v1.x)
                + p2[hh[0]] * bf2f((short)v2.x) + p3[hh[0]] * bf2f((short)v3.x);
        acc[1] += p0[hh[1]] * bf2f((short)v0.y) + p1[hh[1]] * bf2f((short)v1.y)
                + p2[hh[1]] * bf2f((short)v2.y) + p3[hh[1]] * bf2f((short)v3.y);
        acc[2] += p0[hh[2]] * bf2f((short)v0.z) + p1[hh[2]] * bf2f((short)v1.z)
                + p2[hh[2]] * bf2f((short)v2.z) + p3[hh[2]] * bf2f((short)v3.z);
        acc[3] += p0[hh[3]] * bf2f((short)v0.w) + p1[hh[3]] * bf2f((short)v1.w)
                + p2[hh[3]] * bf2f((short)v2.w) + p3[hh[3]] * bf2f((short)v3.w);
    }
    for (; j < e; j++) {
        int src = ssrc[j];
        ushort4 v = *(const ushort4*)(xh_bf + (size_t)src * FEAT + f0);
        const float* pj = p + (size_t)j * NHEAD;
        acc[0] += pj[hh[0]] * bf2f((short)v.x);
        acc[1] += pj[hh[1]] * bf2f((short)v.y);
        acc[2] += pj[hh[2]] * bf2f((short)v.z);
        acc[3] += pj[hh[3]] * bf2f((short)v.w);
    }

    // fold softmax denominator (per head)
    const float* dv = dinv + (size_t)n * NHEAD;
#pragma unroll
    for (int i = 0; i < 4; i++) acc[i] *= dv[hh[i]];

    float4 bv = *(const float4*)(b_att + f0);
    float4 gv = *(const float4*)(gamma + f0);
    float4 be = *(const float4*)(beta + f0);
    float4 mv = *(const float4*)(mean + f0);
    float4 vv = *(const float4*)(var + f0);
    float z[4] = {acc[0] + bv.x, acc[1] + bv.y, acc[2] + bv.z, acc[3] + bv.w};
    if (prev_f) {
        float4 pv = *(const float4*)(prev_f + (size_t)n * FEAT + f0);
        z[0] += pv.x; z[1] += pv.y; z[2] += pv.z; z[3] += pv.w;
    }
    if (prev_bf) {
        ushort4 pv = *(const ushort4*)(prev_bf + (size_t)n * KP + f0);
        z[0] += bf2f((short)pv.x); z[1] += bf2f((short)pv.y);
        z[2] += bf2f((short)pv.z); z[3] += bf2f((short)pv.w);
    }
    float g4[4] = {gv.x, gv.y, gv.z, gv.w};
    float b4[4] = {be.x, be.y, be.z, be.w};
    float m4[4] = {mv.x, mv.y, mv.z, mv.w};
    float v4[4] = {vv.x, vv.y, vv.z, vv.w};
    ushort4 o;
    unsigned short* op = (unsigned short*)&o;
#pragma unroll
    for (int i = 0; i < 4; i++) {
        float zz = (z[i] - m4[i]) * rsqrtf(v4[i] + BN_EPS) * g4[i] + b4[i];
        op[i] = (unsigned short)f2bf(fmaxf(zz, 0.f));
    }
    *(ushort4*)(hout_bf + (size_t)n * KP + f0) = o;
}

// ---------------- pooling over contiguous node ranges ----------------
__global__ __launch_bounds__(320) void pool_k(const short* __restrict__ h,
                                              const int* __restrict__ gstart,
                                              float* __restrict__ pooled) {
    int g = blockIdx.x;
    int t = threadIdx.x;
    if (t >= 260) return;
    int f0 = t * 4;
    int s = gstart[g], e = gstart[g + 1];
    float acc[4] = {0.f, 0.f, 0.f, 0.f};
    int n = s;
    for (; n + 4 <= e; n += 4) {
        ushort4 v0 = *(const ushort4*)(h + (size_t)n * KP + f0);
        ushort4 v1 = *(const ushort4*)(h + (size_t)(n + 1) * KP + f0);
        ushort4 v2 = *(const ushort4*)(h + (size_t)(n + 2) * KP + f0);
        ushort4 v3 = *(const ushort4*)(h + (size_t)(n + 3) * KP + f0);
        acc[0] += bf2f((short)v0.x) + bf2f((short)v1.x) + bf2f((short)v2.x) + bf2f((short)v3.x);
        acc[1] += bf2f((short)v0.y) + bf2f((short)v1.y) + bf2f((short)v2.y) + bf2f((short)v3.y);
        acc[2] += bf2f((short)v0.z) + bf2f((short)v1.z) + bf2f((short)v2.z) + bf2f((short)v3.z);
        acc[3] += bf2f((short)v0.w) + bf2f((short)v1.w) + bf2f((short)v2.w) + bf2f((short)v3.w);
    }
    for (; n < e; n++) {
        ushort4 v = *(const ushort4*)(h + (size_t)n * KP + f0);
        acc[0] += bf2f((short)v.x);
        acc[1] += bf2f((short)v.y);
        acc[2] += bf2f((short)v.z);
        acc[3] += bf2f((short)v.w);
    }
    *(float4*)(pooled + (size_t)g * FEAT + f0) = make_float4(acc[0], acc[1], acc[2], acc[3]);
}

__global__ void final_k(const float* __restrict__ pooled, const int* __restrict__ gstart,
                        const float* __restrict__ W_out, const float* __restrict__ b_out,
                        float* __restrict__ out) {
    int g = blockIdx.x >> 1, c = blockIdx.x & 1;
    int lane = threadIdx.x;  // 64
    float ssum = 0.f;
    for (int f = lane; f < FEAT; f += 64) ssum += pooled[(size_t)g * FEAT + f] * W_out[f * 2 + c];
#pragma unroll
    for (int o = 1; o < 64; o <<= 1) ssum += __shfl_xor(ssum, o);
    if (lane == 0) {
        float cnt = (float)(gstart[g + 1] - gstart[g]);
        float inv = 1.0f / fmaxf(cnt, 1.0f);
        out[g * 2 + c] = ssum * inv + b_out[c];
    }
}

// ---------------- launch ----------------
extern "C" void kernel_launch(void* const* d_in, const int* in_sizes, int n_in,
                              void* d_out, int out_size, void* d_ws, size_t ws_size,
                              hipStream_t stream) {
    const float* x       = (const float*)d_in[0];
    const int*   ei      = (const int*)d_in[1];
    const int*   batch   = (const int*)d_in[2];
    const float* W       = (const float*)d_in[3];
    const float* a_src   = (const float*)d_in[4];
    const float* a_dst   = (const float*)d_in[5];
    const float* b_att   = (const float*)d_in[6];
    const float* gamma   = (const float*)d_in[7];
    const float* beta    = (const float*)d_in[8];
    const float* r_mean  = (const float*)d_in[9];
    const float* r_var   = (const float*)d_in[10];
    const float* W_out   = (const float*)d_in[11];
    const float* b_out   = (const float*)d_in[12];
    float* out = (float*)d_out;

    const int N = in_sizes[0] / FEAT;
    const int E = in_sizes[1] / 2;
    const int E2 = E + N;
    const int MT = (N + 127) / 128;
    const int Mp = MT * 128;
    const int MTpad = ((MT + 7) / 8) * 8;   // for XCD-swizzled grid

    char* w = (char*)d_ws;
    auto alloc = [&](size_t bytes) {
        void* pp = (void*)w;
        w += (bytes + 255) & ~(size_t)255;
        return pp;
    };
    short* xh_bf  = (short*)alloc((size_t)N * FEAT * 2);
    short* x_bf   = (short*)alloc((size_t)Mp * KP * 2);   // layer-0 A; reused as layer-3 h
    short* hA_bf  = (short*)alloc((size_t)Mp * KP * 2);
    short* hB_bf  = (short*)alloc((size_t)Mp * KP * 2);
    short* Bt3    = (short*)alloc((size_t)NLAYER * NP * KP * 2);
    float* p      = (float*)alloc((size_t)E2 * NHEAD * 4);
    float* asrc   = (float*)alloc((size_t)N * NHEAD * 4);
    float* adst   = (float*)alloc((size_t)N * NHEAD * 4);
    float* dinv   = (float*)alloc((size_t)N * NHEAD * 4);
    int*   src2   = (int*)alloc((size_t)E2 * 4);
    int*   dst2   = (int*)alloc((size_t)E2 * 4);
    int*   ssrc   = (int*)alloc((size_t)E2 * 4);
    int*   sdst   = (int*)alloc((size_t)E2 * 4);
    int*   deg    = (int*)alloc((size_t)N * 4);
    int*   off    = (int*)alloc((size_t)(N + 1) * 4);
    int*   cursor = (int*)alloc((size_t)N * 4);
    int*   gstart = (int*)alloc((size_t)(NGRAPH + 1) * 4);
    float* pooled = (float*)alloc((size_t)NGRAPH * FEAT * 4);

    hipMemsetAsync(deg, 0, (size_t)N * 4, stream);
    hipMemsetAsync(Bt3, 0, (size_t)NLAYER * NP * KP * 2, stream);

    conv_x_bf<<<(N * FEAT + 255) / 256, 256, 0, stream>>>(x, x_bf, N);
    pad_bf<<<Mp, 64, 0, stream>>>(x_bf, N);
    pad_bf<<<Mp, 64, 0, stream>>>(hA_bf, N);
    pad_bf<<<Mp, 64, 0, stream>>>(hB_bf, N);
    dim3 tgrid((FEAT + 31) / 32, (FEAT + 31) / 32);
    for (int l = 0; l < NLAYER; l++)
        transpose_w<<<tgrid, 256, 0, stream>>>(W + (size_t)l * FEAT * FEAT,
                                               Bt3 + (size_t)l * NP * KP);
    wa_kernel<<<(NLAYER * FEAT * NHEAD + 255) / 256, 256, 0, stream>>>(W, a_src, a_dst, Bt3);

    build_edges<<<(E2 + 255) / 256, 256, 0, stream>>>(ei, E, N, src2, dst2, deg);
    scan_kernel<<<1, 1024, 0, stream>>>(deg, off, cursor, N);
    scatter_k<<<(E2 + 255) / 256, 256, 0, stream>>>(src2, dst2, cursor, ssrc, sdst, E2);
    gstart_k<<<(N + 255) / 256, 256, 0, stream>>>(batch, gstart, N);

    const short* hin[NLAYER]     = {x_bf, hA_bf, hB_bf};
    const float* prevf[NLAYER]   = {nullptr, x, nullptr};
    const short* prevbf[NLAYER]  = {nullptr, nullptr, hA_bf};
    short* houtl[NLAYER]         = {hA_bf, hB_bf, x_bf};

    for (int l = 0; l < NLAYER; l++) {
        gemm_mfma<<<MTpad * 9, 256, 0, stream>>>(hin[l], Bt3 + (size_t)l * NP * KP,
                                                 xh_bf, asrc, adst, N, MT);
        att_softmax<<<(N * NHEAD + 255) / 256, 256, 0, stream>>>(off, ssrc, asrc, adst, p, dinv, N);
        aggregate<<<N, 320, 0, stream>>>(xh_bf, p, dinv, off, ssrc, prevf[l], prevbf[l],
                                         b_att + l * FEAT, gamma + l * FEAT, beta + l * FEAT,
                                         r_mean + l * FEAT, r_var + l * FEAT,
                                         houtl[l], N);
    }

    pool_k<<<NGRAPH, 320, 0, stream>>>(x_bf, gstart, pooled);
    final_k<<<NGRAPH * 2, 64, 0, stream>>>(pooled, gstart, W_out, b_out, out);
}